// Round 1
// baseline (187799.963 us; speedup 1.0000x reference)
//
#include <hip/hip_runtime.h>

// ---------------------------------------------------------------------------
// CommNet: 4x conv3d(+PReLU, 3x with maxpool2) then 3 comm-FC layers.
// B=16, A=5 -> N=80 samples through the conv stack.
// Round 1: correctness-first fp32 direct conv, fused bias+PReLU+pool.
// ---------------------------------------------------------------------------

// Fused conv3d (stride 1) + bias + PReLU + 2x2x2 maxpool, NCDHW.
// One thread per pooled output. Block handles a single (n, oc) pair slice so
// the oc's weights (CIN*K^3 floats) stage into LDS once.
template<int CIN, int K, int PAD, int SIN, int SPOOL>
__global__ void conv_pool_kernel(const float* __restrict__ in,
                                 const float* __restrict__ w,
                                 const float* __restrict__ bias,
                                 const float* __restrict__ slope,
                                 float* __restrict__ out,
                                 float scale)
{
    const int oc   = blockIdx.y;
    const int n    = blockIdx.z;
    const int COUT = gridDim.y;

    __shared__ float wsh[CIN * K * K * K];
    for (int i = threadIdx.x; i < CIN * K * K * K; i += blockDim.x)
        wsh[i] = w[oc * CIN * K * K * K + i];
    __syncthreads();

    const int POS = SPOOL * SPOOL * SPOOL;
    int idx = blockIdx.x * blockDim.x + threadIdx.x;
    if (idx >= POS) return;

    int px = idx % SPOOL;
    int py = (idx / SPOOL) % SPOOL;
    int pz = idx / (SPOOL * SPOOL);

    // base input coordinate (includes -PAD shift); conv output (2p+d), tap k
    // reads input (2p - PAD + k + d)
    int bz = 2 * pz - PAD, by = 2 * py - PAD, bx = 2 * px - PAD;

    float acc[2][2][2] = {};
    const float* inb = in + (long)n * CIN * SIN * SIN * SIN;

    for (int ic = 0; ic < CIN; ++ic) {
        const float* inc = inb + (long)ic * SIN * SIN * SIN;
        for (int kz = 0; kz < K; ++kz) {
            int iz0 = bz + kz;
            for (int ky = 0; ky < K; ++ky) {
                int iy0 = by + ky;
                float wv[K];
                #pragma unroll
                for (int kx = 0; kx < K; ++kx)
                    wv[kx] = wsh[((ic * K + kz) * K + ky) * K + kx];

                float inv[2][2][K + 1];
                #pragma unroll
                for (int dz = 0; dz < 2; ++dz) {
                    int iz = iz0 + dz;
                    bool zok = (unsigned)iz < (unsigned)SIN;
                    #pragma unroll
                    for (int dy = 0; dy < 2; ++dy) {
                        int iy = iy0 + dy;
                        bool yok = zok && ((unsigned)iy < (unsigned)SIN);
                        const float* row = inc + ((long)iz * SIN + iy) * SIN;
                        #pragma unroll
                        for (int xx = 0; xx < K + 1; ++xx) {
                            int ix = bx + xx;
                            bool ok = yok && ((unsigned)ix < (unsigned)SIN);
                            inv[dz][dy][xx] = ok ? row[ix] : 0.f;
                        }
                    }
                }
                #pragma unroll
                for (int dz = 0; dz < 2; ++dz)
                    #pragma unroll
                    for (int dy = 0; dy < 2; ++dy)
                        #pragma unroll
                        for (int kx = 0; kx < K; ++kx)
                            #pragma unroll
                            for (int dx = 0; dx < 2; ++dx)
                                acc[dz][dy][dx] += wv[kx] * inv[dz][dy][kx + dx];
            }
        }
    }

    float b = bias[oc];
    float a = slope[0];
    float m = -3.4e38f;
    #pragma unroll
    for (int dz = 0; dz < 2; ++dz)
        #pragma unroll
        for (int dy = 0; dy < 2; ++dy)
            #pragma unroll
            for (int dx = 0; dx < 2; ++dx) {
                float v = acc[dz][dy][dx] * scale + b;
                v = (v >= 0.f) ? v : a * v;
                m = fmaxf(m, v);
            }

    out[(((long)n * COUT + oc) * SPOOL + pz) * SPOOL * SPOOL + py * SPOOL + px] = m;
}

// conv3: 64->64ch, k3, pad 0, in 4^3 -> out 2^3, + bias + PReLU (no pool).
__global__ void conv3_kernel(const float* __restrict__ in,
                             const float* __restrict__ w,
                             const float* __restrict__ bias,
                             const float* __restrict__ slope,
                             float* __restrict__ out)
{
    int idx = blockIdx.x * blockDim.x + threadIdx.x;
    const int TOTAL = 80 * 64 * 8;
    if (idx >= TOTAL) return;
    int p  = idx & 7;
    int oc = (idx >> 3) & 63;
    int n  = idx >> 9;
    int ox = p & 1, oy = (p >> 1) & 1, oz = p >> 2;

    const float* inb = in + (long)n * 64 * 64;   // 64 ch * 4^3
    const float* wb  = w + (long)oc * 64 * 27;

    float acc = 0.f;
    for (int ic = 0; ic < 64; ++ic) {
        const float* inc = inb + ic * 64;
        const float* wc  = wb + ic * 27;
        #pragma unroll
        for (int kz = 0; kz < 3; ++kz)
            #pragma unroll
            for (int ky = 0; ky < 3; ++ky)
                #pragma unroll
                for (int kx = 0; kx < 3; ++kx)
                    acc += wc[(kz * 3 + ky) * 3 + kx] *
                           inc[((oz + kz) * 4 + (oy + ky)) * 4 + (ox + kx)];
    }
    float v = acc + bias[oc];
    float a = slope[0];
    v = (v >= 0.f) ? v : a * v;
    out[idx] = v;
}

// comm-FC: out[b,a,o] = dot(cat(feat[b,a,:], mean_a feat[b,:,:]), w[a,o,:]) + bias[a,o]
// feat [16][5][D], w [5][O][2D], bias [5][O], out [16][5][O]
template<int D, int O, bool PRELU_ON>
__global__ void comm_fc_kernel(const float* __restrict__ feat,
                               const float* __restrict__ w,
                               const float* __restrict__ bias,
                               const float* __restrict__ slope,
                               float* __restrict__ out)
{
    const int a = blockIdx.x;   // agent
    const int b = blockIdx.y;   // batch

    __shared__ __align__(16) float cat[2 * D];
    for (int i = threadIdx.x; i < D; i += blockDim.x) {
        float m = 0.f;
        #pragma unroll
        for (int aa = 0; aa < 5; ++aa) m += feat[(b * 5 + aa) * D + i];
        cat[i]     = feat[(b * 5 + a) * D + i];
        cat[D + i] = m * 0.2f;
    }
    __syncthreads();

    for (int o = threadIdx.x; o < O; o += blockDim.x) {
        const float4* wr = (const float4*)(w + ((long)(a * O) + o) * 2 * D);
        const float4* cr = (const float4*)cat;
        float acc = 0.f;
        for (int i = 0; i < 2 * D / 4; ++i) {
            float4 wv = wr[i];
            float4 cv = cr[i];
            acc += wv.x * cv.x + wv.y * cv.y + wv.z * cv.z + wv.w * cv.w;
        }
        acc += bias[a * O + o];
        if constexpr (PRELU_ON) {
            float s = slope[0];
            acc = (acc >= 0.f) ? acc : s * acc;
        }
        out[(b * 5 + a) * O + o] = acc;
    }
}

extern "C" void kernel_launch(void* const* d_in, const int* in_sizes, int n_in,
                              void* d_out, int out_size, void* d_ws, size_t ws_size,
                              hipStream_t stream)
{
    const float* x    = (const float*)d_in[0];
    const float* c0w  = (const float*)d_in[1];
    const float* c0b  = (const float*)d_in[2];
    const float* p0   = (const float*)d_in[3];
    const float* c1w  = (const float*)d_in[4];
    const float* c1b  = (const float*)d_in[5];
    const float* p1   = (const float*)d_in[6];
    const float* c2w  = (const float*)d_in[7];
    const float* c2b  = (const float*)d_in[8];
    const float* p2   = (const float*)d_in[9];
    const float* c3w  = (const float*)d_in[10];
    const float* c3b  = (const float*)d_in[11];
    const float* p3   = (const float*)d_in[12];
    const float* f1w  = (const float*)d_in[13];
    const float* f1b  = (const float*)d_in[14];
    const float* p4   = (const float*)d_in[15];
    const float* f2w  = (const float*)d_in[16];
    const float* f2b  = (const float*)d_in[17];
    const float* p5   = (const float*)d_in[18];
    const float* f3w  = (const float*)d_in[19];
    const float* f3b  = (const float*)d_in[20];

    float* ws    = (float*)d_ws;
    float* buf1  = ws;                       // 80*32*21^3 = 23,708,160
    float* buf2  = buf1 + 23708160;          // 80*32*9^3  =  1,866,240
    float* buf3  = buf2 + 1866240;           // 80*64*4^3  =    327,680
    float* feat0 = buf3 + 327680;            // 80*64*8    =     40,960
    float* feat1 = feat0 + 40960;            // 16*5*256   =     20,480
    float* feat2 = feat1 + 20480;            // 16*5*128   =     10,240

    // conv0: 4->32, k5 pad1, 45^3 -> conv 43^3 -> pool 21^3 (9261 pos)
    conv_pool_kernel<4, 5, 1, 45, 21>
        <<<dim3(37, 32, 80), dim3(256), 0, stream>>>(x, c0w, c0b, p0, buf1, 1.f / 255.f);

    // conv1: 32->32, k5 pad1, 21^3 -> conv 19^3 -> pool 9^3 (729 pos)
    conv_pool_kernel<32, 5, 1, 21, 9>
        <<<dim3(3, 32, 80), dim3(256), 0, stream>>>(buf1, c1w, c1b, p1, buf2, 1.f);

    // conv2: 32->64, k4 pad1, 9^3 -> conv 8^3 -> pool 4^3 (64 pos)
    conv_pool_kernel<32, 4, 1, 9, 4>
        <<<dim3(1, 64, 80), dim3(64), 0, stream>>>(buf2, c2w, c2b, p2, buf3, 1.f);

    // conv3: 64->64, k3 pad0, 4^3 -> 2^3
    conv3_kernel<<<dim3(160), dim3(256), 0, stream>>>(buf3, c3w, c3b, p3, feat0);

    // comm FC stack
    comm_fc_kernel<512, 256, true>
        <<<dim3(5, 16), dim3(256), 0, stream>>>(feat0, f1w, f1b, p4, feat1);
    comm_fc_kernel<256, 128, true>
        <<<dim3(5, 16), dim3(256), 0, stream>>>(feat1, f2w, f2b, p5, feat2);
    comm_fc_kernel<128, 6, false>
        <<<dim3(5, 16), dim3(64), 0, stream>>>(feat2, f3w, f3b, nullptr, (float*)d_out);
}

// Round 2
// 124123.694 us; speedup vs baseline: 1.5130x; 1.5130x over previous
//
#include <hip/hip_runtime.h>

// ---------------------------------------------------------------------------
// CommNet: 4x conv3d(+PReLU, 3x with maxpool2) then 3 comm-FC layers.
// B=16, A=5 -> N=80 samples through the conv stack.
// Round 2: kill scratch spill (launch_bounds 256,2 -> 128 VGPR budget) and
// register-block PX pooled outputs along x (3 FMA per load instead of 1.67).
// ---------------------------------------------------------------------------

// Fused conv3d (stride 1) + bias + PReLU + 2x2x2 maxpool, NCDHW.
// One thread per PX pooled outputs along x. Block handles a single (n, oc)
// so the oc's weights (CIN*K^3 floats) stage into LDS once.
// Requires SPOOL % PX == 0.
template<int CIN, int K, int PAD, int SIN, int SPOOL, int PX>
__global__ __launch_bounds__(256, 2)
void conv_pool_kernel(const float* __restrict__ in,
                      const float* __restrict__ w,
                      const float* __restrict__ bias,
                      const float* __restrict__ slope,
                      float* __restrict__ out,
                      float scale)
{
    const int oc   = blockIdx.y;
    const int n    = blockIdx.z;
    const int COUT = gridDim.y;

    constexpr int NX = 2 * PX;          // conv outputs in x per thread
    constexpr int LX = 2 * PX + K - 1;  // input span in x per thread
    constexpr int XT = SPOOL / PX;      // thread columns in x

    __shared__ float wsh[CIN * K * K * K];
    for (int i = threadIdx.x; i < CIN * K * K * K; i += blockDim.x)
        wsh[i] = w[oc * CIN * K * K * K + i];
    __syncthreads();

    const int POS = XT * SPOOL * SPOOL;
    int idx = blockIdx.x * blockDim.x + threadIdx.x;
    if (idx >= POS) return;

    int xt = idx % XT;
    int py = (idx / XT) % SPOOL;
    int pz = idx / (XT * SPOOL);
    int px0 = xt * PX;

    // conv output (2p+d) reads input (2p - PAD + k + d)
    int bz = 2 * pz - PAD, by = 2 * py - PAD, bx = 2 * px0 - PAD;

    float acc[2][2][NX] = {};
    const float* inb = in + (long)n * CIN * SIN * SIN * SIN;

    for (int ic = 0; ic < CIN; ++ic) {
        const float* inc = inb + (long)ic * SIN * SIN * SIN;
        for (int kz = 0; kz < K; ++kz) {
            int iz0 = bz + kz;
            for (int ky = 0; ky < K; ++ky) {
                int iy0 = by + ky;
                float wv[K];
                #pragma unroll
                for (int kx = 0; kx < K; ++kx)
                    wv[kx] = wsh[((ic * K + kz) * K + ky) * K + kx];

                float inv[2][2][LX];
                #pragma unroll
                for (int dz = 0; dz < 2; ++dz) {
                    int iz = iz0 + dz;
                    bool zok = (unsigned)iz < (unsigned)SIN;
                    #pragma unroll
                    for (int dy = 0; dy < 2; ++dy) {
                        int iy = iy0 + dy;
                        bool yok = zok && ((unsigned)iy < (unsigned)SIN);
                        const float* row = inc + ((long)iz * SIN + iy) * SIN;
                        #pragma unroll
                        for (int xx = 0; xx < LX; ++xx) {
                            int ix = bx + xx;
                            bool ok = yok && ((unsigned)ix < (unsigned)SIN);
                            inv[dz][dy][xx] = ok ? row[ix] : 0.f;
                        }
                    }
                }
                #pragma unroll
                for (int dz = 0; dz < 2; ++dz)
                    #pragma unroll
                    for (int dy = 0; dy < 2; ++dy)
                        #pragma unroll
                        for (int kx = 0; kx < K; ++kx)
                            #pragma unroll
                            for (int dx = 0; dx < NX; ++dx)
                                acc[dz][dy][dx] += wv[kx] * inv[dz][dy][kx + dx];
            }
        }
    }

    float b = bias[oc];
    float a = slope[0];
    long obase = (((long)n * COUT + oc) * SPOOL + pz) * SPOOL * SPOOL + py * SPOOL + px0;
    #pragma unroll
    for (int j = 0; j < PX; ++j) {
        float m = -3.4e38f;
        #pragma unroll
        for (int dz = 0; dz < 2; ++dz)
            #pragma unroll
            for (int dy = 0; dy < 2; ++dy)
                #pragma unroll
                for (int dx = 0; dx < 2; ++dx) {
                    float v = acc[dz][dy][2 * j + dx] * scale + b;
                    v = (v >= 0.f) ? v : a * v;
                    m = fmaxf(m, v);
                }
        out[obase + j] = m;
    }
}

// conv3: 64->64ch, k3, pad 0, in 4^3 -> out 2^3, + bias + PReLU (no pool).
__global__ void conv3_kernel(const float* __restrict__ in,
                             const float* __restrict__ w,
                             const float* __restrict__ bias,
                             const float* __restrict__ slope,
                             float* __restrict__ out)
{
    int idx = blockIdx.x * blockDim.x + threadIdx.x;
    const int TOTAL = 80 * 64 * 8;
    if (idx >= TOTAL) return;
    int p  = idx & 7;
    int oc = (idx >> 3) & 63;
    int n  = idx >> 9;
    int ox = p & 1, oy = (p >> 1) & 1, oz = p >> 2;

    const float* inb = in + (long)n * 64 * 64;   // 64 ch * 4^3
    const float* wb  = w + (long)oc * 64 * 27;

    float acc = 0.f;
    for (int ic = 0; ic < 64; ++ic) {
        const float* inc = inb + ic * 64;
        const float* wc  = wb + ic * 27;
        #pragma unroll
        for (int kz = 0; kz < 3; ++kz)
            #pragma unroll
            for (int ky = 0; ky < 3; ++ky)
                #pragma unroll
                for (int kx = 0; kx < 3; ++kx)
                    acc += wc[(kz * 3 + ky) * 3 + kx] *
                           inc[((oz + kz) * 4 + (oy + ky)) * 4 + (ox + kx)];
    }
    float v = acc + bias[oc];
    float a = slope[0];
    v = (v >= 0.f) ? v : a * v;
    out[idx] = v;
}

// comm-FC: out[b,a,o] = dot(cat(feat[b,a,:], mean_a feat[b,:,:]), w[a,o,:]) + bias[a,o]
// feat [16][5][D], w [5][O][2D], bias [5][O], out [16][5][O]
template<int D, int O, bool PRELU_ON>
__global__ void comm_fc_kernel(const float* __restrict__ feat,
                               const float* __restrict__ w,
                               const float* __restrict__ bias,
                               const float* __restrict__ slope,
                               float* __restrict__ out)
{
    const int a = blockIdx.x;   // agent
    const int b = blockIdx.y;   // batch

    __shared__ __align__(16) float cat[2 * D];
    for (int i = threadIdx.x; i < D; i += blockDim.x) {
        float m = 0.f;
        #pragma unroll
        for (int aa = 0; aa < 5; ++aa) m += feat[(b * 5 + aa) * D + i];
        cat[i]     = feat[(b * 5 + a) * D + i];
        cat[D + i] = m * 0.2f;
    }
    __syncthreads();

    for (int o = threadIdx.x; o < O; o += blockDim.x) {
        const float4* wr = (const float4*)(w + ((long)(a * O) + o) * 2 * D);
        const float4* cr = (const float4*)cat;
        float acc = 0.f;
        for (int i = 0; i < 2 * D / 4; ++i) {
            float4 wv = wr[i];
            float4 cv = cr[i];
            acc += wv.x * cv.x + wv.y * cv.y + wv.z * cv.z + wv.w * cv.w;
        }
        acc += bias[a * O + o];
        if constexpr (PRELU_ON) {
            float s = slope[0];
            acc = (acc >= 0.f) ? acc : s * acc;
        }
        out[(b * 5 + a) * O + o] = acc;
    }
}

extern "C" void kernel_launch(void* const* d_in, const int* in_sizes, int n_in,
                              void* d_out, int out_size, void* d_ws, size_t ws_size,
                              hipStream_t stream)
{
    const float* x    = (const float*)d_in[0];
    const float* c0w  = (const float*)d_in[1];
    const float* c0b  = (const float*)d_in[2];
    const float* p0   = (const float*)d_in[3];
    const float* c1w  = (const float*)d_in[4];
    const float* c1b  = (const float*)d_in[5];
    const float* p1   = (const float*)d_in[6];
    const float* c2w  = (const float*)d_in[7];
    const float* c2b  = (const float*)d_in[8];
    const float* p2   = (const float*)d_in[9];
    const float* c3w  = (const float*)d_in[10];
    const float* c3b  = (const float*)d_in[11];
    const float* p3   = (const float*)d_in[12];
    const float* f1w  = (const float*)d_in[13];
    const float* f1b  = (const float*)d_in[14];
    const float* p4   = (const float*)d_in[15];
    const float* f2w  = (const float*)d_in[16];
    const float* f2b  = (const float*)d_in[17];
    const float* p5   = (const float*)d_in[18];
    const float* f3w  = (const float*)d_in[19];
    const float* f3b  = (const float*)d_in[20];

    float* ws    = (float*)d_ws;
    float* buf1  = ws;                       // 80*32*21^3 = 23,708,160
    float* buf2  = buf1 + 23708160;          // 80*32*9^3  =  1,866,240
    float* buf3  = buf2 + 1866240;           // 80*64*4^3  =    327,680
    float* feat0 = buf3 + 327680;            // 80*64*8    =     40,960
    float* feat1 = feat0 + 40960;            // 16*5*256   =     20,480
    float* feat2 = feat1 + 20480;            // 16*5*128   =     10,240

    // conv0: 4->32, k5 pad1, 45^3 -> conv 43^3 -> pool 21^3; PX=3 -> 7*21*21=3087 thr
    conv_pool_kernel<4, 5, 1, 45, 21, 3>
        <<<dim3(13, 32, 80), dim3(256), 0, stream>>>(x, c0w, c0b, p0, buf1, 1.f / 255.f);

    // conv1: 32->32, k5 pad1, 21^3 -> conv 19^3 -> pool 9^3; PX=3 -> 3*9*9=243 thr
    conv_pool_kernel<32, 5, 1, 21, 9, 3>
        <<<dim3(1, 32, 80), dim3(256), 0, stream>>>(buf1, c1w, c1b, p1, buf2, 1.f);

    // conv2: 32->64, k4 pad1, 9^3 -> conv 8^3 -> pool 4^3; PX=2 -> 2*4*4=32 thr
    conv_pool_kernel<32, 4, 1, 9, 4, 2>
        <<<dim3(1, 64, 80), dim3(64), 0, stream>>>(buf2, c2w, c2b, p2, buf3, 1.f);

    // conv3: 64->64, k3 pad0, 4^3 -> 2^3
    conv3_kernel<<<dim3(160), dim3(256), 0, stream>>>(buf3, c3w, c3b, p3, feat0);

    // comm FC stack
    comm_fc_kernel<512, 256, true>
        <<<dim3(5, 16), dim3(256), 0, stream>>>(feat0, f1w, f1b, p4, feat1);
    comm_fc_kernel<256, 128, true>
        <<<dim3(5, 16), dim3(256), 0, stream>>>(feat1, f2w, f2b, p5, feat2);
    comm_fc_kernel<128, 6, false>
        <<<dim3(5, 16), dim3(64), 0, stream>>>(feat2, f3w, f3b, nullptr, (float*)d_out);
}

// Round 3
// 9010.919 us; speedup vs baseline: 20.8414x; 13.7748x over previous
//
#include <hip/hip_runtime.h>

// ---------------------------------------------------------------------------
// CommNet: 4x conv3d(+PReLU, 3x with maxpool2) then 3 comm-FC layers.
// Round 3: row-streaming conv on pre-padded inputs.
//  - loop over input rows (tz,ty); each LX-float row feeds all valid
//    (dz,dy,kx) taps -> every input float loaded once per (thread,ic),
//    8.3 FMA per loaded float, live set ~60 VGPR (no spill).
//  - inputs pre-padded with zero halos -> no bounds checks, aligned float2.
//  - weights via wave-uniform indices -> scalar loads (s_load), no LDS.
// ---------------------------------------------------------------------------

// in: padded NCDHW, z/y dims implied, x stride SXS, channel stride ICS.
// out: padded, dims (SPOOL+2*OPAD)^2 x stride OXS, halo written by memset.
template<int CIN, int K, int SY, int SXS, int ICS, int SPOOL, int PX,
         int OXS, int OPAD>
__global__ __launch_bounds__(256, 4)
void conv_pool_kernel(const float* __restrict__ in,
                      const float* __restrict__ w,
                      const float* __restrict__ bias,
                      const float* __restrict__ slope,
                      float* __restrict__ out,
                      float scale)
{
    constexpr int NX  = 2 * PX;          // conv outputs in x per thread
    constexpr int LX  = NX + K - 1;      // input floats per row
    constexpr int LX2 = (LX + 1) / 2;    // float2 loads per row
    constexpr int XT  = SPOOL / PX;      // thread columns in x
    constexpr int OD  = SPOOL + 2 * OPAD;

    const int oc   = blockIdx.y;
    const int n    = blockIdx.z;
    const int COUT = gridDim.y;

    int idx = blockIdx.x * blockDim.x + threadIdx.x;
    const int POS = XT * SPOOL * SPOOL;
    if (idx >= POS) return;

    int xt  = idx % XT;
    int py  = (idx / XT) % SPOOL;
    int pz  = idx / (XT * SPOOL);
    int px0 = xt * PX;

    // padded input coord for (tz,ty,xx): (2pz+tz, 2py+ty, 2px0+xx)
    const float* inb = in + (long)n * CIN * ICS + (2 * pz * SY + 2 * py) * SXS + 2 * px0;
    const float* wb  = w + (long)oc * CIN * K * K * K;

    float acc[2][2][NX] = {};

    for (int ic = 0; ic < CIN; ++ic) {
        const float* inc = inb + ic * ICS;
        const float* wic = wb + ic * K * K * K;
        #pragma unroll
        for (int tz = 0; tz < K + 1; ++tz) {
            #pragma unroll
            for (int ty = 0; ty < K + 1; ++ty) {
                const float2* rp = (const float2*)(inc + (tz * SY + ty) * SXS);
                float row[LX2 * 2];
                #pragma unroll
                for (int i = 0; i < LX2; ++i) {
                    float2 t = rp[i];
                    row[2 * i] = t.x; row[2 * i + 1] = t.y;
                }
                #pragma unroll
                for (int dz = 0; dz < 2; ++dz) {
                    if (tz - dz < 0 || tz - dz >= K) continue;  // folds at compile time
                    #pragma unroll
                    for (int dy = 0; dy < 2; ++dy) {
                        if (ty - dy < 0 || ty - dy >= K) continue;
                        const float* wrow = wic + ((tz - dz) * K + (ty - dy)) * K;
                        #pragma unroll
                        for (int kx = 0; kx < K; ++kx) {
                            float wv = wrow[kx];   // wave-uniform -> s_load
                            #pragma unroll
                            for (int dx = 0; dx < NX; ++dx)
                                acc[dz][dy][dx] += wv * row[kx + dx];
                        }
                    }
                }
            }
        }
    }

    float b = bias[oc];
    float a = slope[0];
    long ob = ((long)n * COUT + oc) * (OD * OD * OXS)
            + (long)(pz + OPAD) * (OD * OXS) + (py + OPAD) * OXS + OPAD + px0;
    #pragma unroll
    for (int j = 0; j < PX; ++j) {
        float m = -3.4e38f;
        #pragma unroll
        for (int dz = 0; dz < 2; ++dz)
            #pragma unroll
            for (int dy = 0; dy < 2; ++dy)
                #pragma unroll
                for (int dx = 0; dx < 2; ++dx) {
                    float v = acc[dz][dy][2 * j + dx] * scale + b;
                    v = (v >= 0.f) ? v : a * v;
                    m = fmaxf(m, v);
                }
        out[ob + j] = m;
    }
}

// Copy x [80*4][45][45][45] into zeroed padded P0 [80*4][47][47][48] at +1.
__global__ void pad_input_kernel(const float* __restrict__ x,
                                 float* __restrict__ P0)
{
    long idx = (long)blockIdx.x * blockDim.x + threadIdx.x;
    const long TOTAL = 80L * 4 * 45 * 45 * 45;
    if (idx >= TOTAL) return;
    int  ix = (int)(idx % 45);
    long t  = idx / 45;
    int  iy = (int)(t % 45);
    t /= 45;
    int  iz = (int)(t % 45);
    long nc = t / 45;
    P0[nc * 106032 + (iz + 1) * 2256 + (iy + 1) * 48 + (ix + 1)] = x[idx];
}

// conv3: 64->64ch, k3, pad 0, in 4^3 -> out 2^3, + bias + PReLU (no pool).
__global__ void conv3_kernel(const float* __restrict__ in,
                             const float* __restrict__ w,
                             const float* __restrict__ bias,
                             const float* __restrict__ slope,
                             float* __restrict__ out)
{
    int idx = blockIdx.x * blockDim.x + threadIdx.x;
    const int TOTAL = 80 * 64 * 8;
    if (idx >= TOTAL) return;
    int p  = idx & 7;
    int oc = (idx >> 3) & 63;
    int n  = idx >> 9;
    int ox = p & 1, oy = (p >> 1) & 1, oz = p >> 2;

    const float* inb = in + (long)n * 64 * 64;
    const float* wb  = w + (long)oc * 64 * 27;

    float acc = 0.f;
    for (int ic = 0; ic < 64; ++ic) {
        const float* inc = inb + ic * 64;
        const float* wc  = wb + ic * 27;
        #pragma unroll
        for (int kz = 0; kz < 3; ++kz)
            #pragma unroll
            for (int ky = 0; ky < 3; ++ky)
                #pragma unroll
                for (int kx = 0; kx < 3; ++kx)
                    acc += wc[(kz * 3 + ky) * 3 + kx] *
                           inc[((oz + kz) * 4 + (oy + ky)) * 4 + (ox + kx)];
    }
    float v = acc + bias[oc];
    float a = slope[0];
    v = (v >= 0.f) ? v : a * v;
    out[idx] = v;
}

// comm-FC: out[b,a,o] = dot(cat(feat[b,a,:], mean_a feat[b,:,:]), w[a,o,:]) + bias[a,o]
template<int D, int O, bool PRELU_ON>
__global__ void comm_fc_kernel(const float* __restrict__ feat,
                               const float* __restrict__ w,
                               const float* __restrict__ bias,
                               const float* __restrict__ slope,
                               float* __restrict__ out)
{
    const int a = blockIdx.x;
    const int b = blockIdx.y;

    __shared__ __align__(16) float cat[2 * D];
    for (int i = threadIdx.x; i < D; i += blockDim.x) {
        float m = 0.f;
        #pragma unroll
        for (int aa = 0; aa < 5; ++aa) m += feat[(b * 5 + aa) * D + i];
        cat[i]     = feat[(b * 5 + a) * D + i];
        cat[D + i] = m * 0.2f;
    }
    __syncthreads();

    for (int o = threadIdx.x; o < O; o += blockDim.x) {
        const float4* wr = (const float4*)(w + ((long)(a * O) + o) * 2 * D);
        const float4* cr = (const float4*)cat;
        float acc = 0.f;
        for (int i = 0; i < 2 * D / 4; ++i) {
            float4 wv = wr[i];
            float4 cv = cr[i];
            acc += wv.x * cv.x + wv.y * cv.y + wv.z * cv.z + wv.w * cv.w;
        }
        acc += bias[a * O + o];
        if constexpr (PRELU_ON) {
            float s = slope[0];
            acc = (acc >= 0.f) ? acc : s * acc;
        }
        out[(b * 5 + a) * O + o] = acc;
    }
}

extern "C" void kernel_launch(void* const* d_in, const int* in_sizes, int n_in,
                              void* d_out, int out_size, void* d_ws, size_t ws_size,
                              hipStream_t stream)
{
    const float* x    = (const float*)d_in[0];
    const float* c0w  = (const float*)d_in[1];
    const float* c0b  = (const float*)d_in[2];
    const float* p0   = (const float*)d_in[3];
    const float* c1w  = (const float*)d_in[4];
    const float* c1b  = (const float*)d_in[5];
    const float* p1   = (const float*)d_in[6];
    const float* c2w  = (const float*)d_in[7];
    const float* c2b  = (const float*)d_in[8];
    const float* p2   = (const float*)d_in[9];
    const float* c3w  = (const float*)d_in[10];
    const float* c3b  = (const float*)d_in[11];
    const float* p3   = (const float*)d_in[12];
    const float* f1w  = (const float*)d_in[13];
    const float* f1b  = (const float*)d_in[14];
    const float* p4   = (const float*)d_in[15];
    const float* f2w  = (const float*)d_in[16];
    const float* f2b  = (const float*)d_in[17];
    const float* p5   = (const float*)d_in[18];
    const float* f3w  = (const float*)d_in[19];
    const float* f3b  = (const float*)d_in[20];

    float* ws = (float*)d_ws;
    // Region A first holds P0 (conv0 input); after conv0, P0 is dead and A is
    // reused for P2/P3/feats. P1 must coexist with both -> placed after A.
    float* P0    = ws;                       // 80*4*47*47*48 = 33,930,240 floats
    float* P1    = ws + 33930240;            // 80*32*23*23*24 = 32,501,760
    float* P2    = ws;                       // 80*32*11*11*12 =  3,717,120 (aliases dead P0)
    float* P3    = ws + 3717120;             // 80*64*4^3      =    327,680
    float* feat0 = P3 + 327680;              // 80*512
    float* feat1 = feat0 + 40960;            // 16*5*256
    float* feat2 = feat1 + 20480;            // 16*5*128

    // zero P0 (halos) + P1 (halos); 265 MB ~ 42 us
    hipMemsetAsync(ws, 0, (33930240L + 32501760L) * sizeof(float), stream);
    pad_input_kernel<<<(29160000 + 255) / 256, 256, 0, stream>>>(x, P0);

    // conv0: 4->32, k5, in padded [47][47][48], out padded [23][23][24]; PX=3
    conv_pool_kernel<4, 5, 47, 48, 106032, 21, 3, 24, 1>
        <<<dim3(13, 32, 80), dim3(256), 0, stream>>>(P0, c0w, c0b, p0, P1, 1.f / 255.f);

    // zero P2 halos (P0 now dead)
    hipMemsetAsync(P2, 0, 3717120L * sizeof(float), stream);

    // conv1: 32->32, k5, in padded [23][23][24], out padded [11][11][12]; PX=3
    conv_pool_kernel<32, 5, 23, 24, 12696, 9, 3, 12, 1>
        <<<dim3(1, 32, 80), dim3(256), 0, stream>>>(P1, c1w, c1b, p1, P2, 1.f);

    // conv2: 32->64, k4, in padded [11][11][12], out plain [4][4][4]; PX=1
    conv_pool_kernel<32, 4, 11, 12, 1452, 4, 1, 4, 0>
        <<<dim3(1, 64, 80), dim3(64), 0, stream>>>(P2, c2w, c2b, p2, P3, 1.f);

    // conv3: 64->64, k3 pad0, 4^3 -> 2^3
    conv3_kernel<<<dim3(160), dim3(256), 0, stream>>>(P3, c3w, c3b, p3, feat0);

    // comm FC stack
    comm_fc_kernel<512, 256, true>
        <<<dim3(5, 16), dim3(256), 0, stream>>>(feat0, f1w, f1b, p4, feat1);
    comm_fc_kernel<256, 128, true>
        <<<dim3(5, 16), dim3(256), 0, stream>>>(feat1, f2w, f2b, p5, feat2);
    comm_fc_kernel<128, 6, false>
        <<<dim3(5, 16), dim3(64), 0, stream>>>(feat2, f3w, f3b, nullptr, (float*)d_out);
}

// Round 4
// 5696.243 us; speedup vs baseline: 32.9691x; 1.5819x over previous
//
#include <hip/hip_runtime.h>

// ---------------------------------------------------------------------------
// CommNet: 4x conv3d(+PReLU, 3x with maxpool2) then 3 comm-FC layers.
// Round 4: row-streaming conv on pre-padded inputs, spill actually fixed.
//  - __launch_bounds__(256,2): 128+ VGPR budget (R2-verified; (256,4) gave
//    a 64-reg budget and 5.3 GB of scratch spill traffic in R3).
//  - #pragma unroll 1 on the ic loop: caps the scheduling window to one
//    input channel so the compiler can't hoist 144 rows of loads.
// ---------------------------------------------------------------------------

// in: padded NCDHW, z/y dims implied, x stride SXS, channel stride ICS.
// out: padded, dims (SPOOL+2*OPAD)^2 x stride OXS, halo written by memset.
template<int CIN, int K, int SY, int SXS, int ICS, int SPOOL, int PX,
         int OXS, int OPAD>
__global__ __launch_bounds__(256, 2)
void conv_pool_kernel(const float* __restrict__ in,
                      const float* __restrict__ w,
                      const float* __restrict__ bias,
                      const float* __restrict__ slope,
                      float* __restrict__ out,
                      float scale)
{
    constexpr int NX  = 2 * PX;          // conv outputs in x per thread
    constexpr int LX  = NX + K - 1;      // input floats per row
    constexpr int LX2 = (LX + 1) / 2;    // float2 loads per row
    constexpr int XT  = SPOOL / PX;      // thread columns in x
    constexpr int OD  = SPOOL + 2 * OPAD;

    const int oc   = blockIdx.y;
    const int n    = blockIdx.z;
    const int COUT = gridDim.y;

    int idx = blockIdx.x * blockDim.x + threadIdx.x;
    const int POS = XT * SPOOL * SPOOL;
    if (idx >= POS) return;

    int xt  = idx % XT;
    int py  = (idx / XT) % SPOOL;
    int pz  = idx / (XT * SPOOL);
    int px0 = xt * PX;

    // padded input coord for (tz,ty,xx): (2pz+tz, 2py+ty, 2px0+xx)
    const float* inb = in + (long)n * CIN * ICS + (2 * pz * SY + 2 * py) * SXS + 2 * px0;
    const float* wb  = w + (long)oc * CIN * K * K * K;

    float acc[2][2][NX] = {};

    #pragma unroll 1
    for (int ic = 0; ic < CIN; ++ic) {
        const float* inc = inb + (long)ic * ICS;
        const float* wic = wb + ic * K * K * K;
        #pragma unroll
        for (int tz = 0; tz < K + 1; ++tz) {
            #pragma unroll
            for (int ty = 0; ty < K + 1; ++ty) {
                const float2* rp = (const float2*)(inc + (tz * SY + ty) * SXS);
                float row[LX2 * 2];
                #pragma unroll
                for (int i = 0; i < LX2; ++i) {
                    float2 t = rp[i];
                    row[2 * i] = t.x; row[2 * i + 1] = t.y;
                }
                #pragma unroll
                for (int dz = 0; dz < 2; ++dz) {
                    if (tz - dz < 0 || tz - dz >= K) continue;  // folds at compile time
                    #pragma unroll
                    for (int dy = 0; dy < 2; ++dy) {
                        if (ty - dy < 0 || ty - dy >= K) continue;
                        const float* wrow = wic + ((tz - dz) * K + (ty - dy)) * K;
                        #pragma unroll
                        for (int kx = 0; kx < K; ++kx) {
                            float wv = wrow[kx];   // wave-uniform -> s_load
                            #pragma unroll
                            for (int dx = 0; dx < NX; ++dx)
                                acc[dz][dy][dx] += wv * row[kx + dx];
                        }
                    }
                }
            }
        }
    }

    float b = bias[oc];
    float a = slope[0];
    long ob = ((long)n * COUT + oc) * (OD * OD * OXS)
            + (long)(pz + OPAD) * (OD * OXS) + (py + OPAD) * OXS + OPAD + px0;
    #pragma unroll
    for (int j = 0; j < PX; ++j) {
        float m = -3.4e38f;
        #pragma unroll
        for (int dz = 0; dz < 2; ++dz)
            #pragma unroll
            for (int dy = 0; dy < 2; ++dy)
                #pragma unroll
                for (int dx = 0; dx < 2; ++dx) {
                    float v = acc[dz][dy][2 * j + dx] * scale + b;
                    v = (v >= 0.f) ? v : a * v;
                    m = fmaxf(m, v);
                }
        out[ob + j] = m;
    }
}

// Copy x [80*4][45][45][45] into zeroed padded P0 [80*4][47][47][48] at +1.
__global__ void pad_input_kernel(const float* __restrict__ x,
                                 float* __restrict__ P0)
{
    long idx = (long)blockIdx.x * blockDim.x + threadIdx.x;
    const long TOTAL = 80L * 4 * 45 * 45 * 45;
    if (idx >= TOTAL) return;
    int  ix = (int)(idx % 45);
    long t  = idx / 45;
    int  iy = (int)(t % 45);
    t /= 45;
    int  iz = (int)(t % 45);
    long nc = t / 45;
    P0[nc * 106032 + (iz + 1) * 2256 + (iy + 1) * 48 + (ix + 1)] = x[idx];
}

// conv3: 64->64ch, k3, pad 0, in 4^3 -> out 2^3, + bias + PReLU (no pool).
__global__ void conv3_kernel(const float* __restrict__ in,
                             const float* __restrict__ w,
                             const float* __restrict__ bias,
                             const float* __restrict__ slope,
                             float* __restrict__ out)
{
    int idx = blockIdx.x * blockDim.x + threadIdx.x;
    const int TOTAL = 80 * 64 * 8;
    if (idx >= TOTAL) return;
    int p  = idx & 7;
    int oc = (idx >> 3) & 63;
    int n  = idx >> 9;
    int ox = p & 1, oy = (p >> 1) & 1, oz = p >> 2;

    const float* inb = in + (long)n * 64 * 64;
    const float* wb  = w + (long)oc * 64 * 27;

    float acc = 0.f;
    for (int ic = 0; ic < 64; ++ic) {
        const float* inc = inb + ic * 64;
        const float* wc  = wb + ic * 27;
        #pragma unroll
        for (int kz = 0; kz < 3; ++kz)
            #pragma unroll
            for (int ky = 0; ky < 3; ++ky)
                #pragma unroll
                for (int kx = 0; kx < 3; ++kx)
                    acc += wc[(kz * 3 + ky) * 3 + kx] *
                           inc[((oz + kz) * 4 + (oy + ky)) * 4 + (ox + kx)];
    }
    float v = acc + bias[oc];
    float a = slope[0];
    v = (v >= 0.f) ? v : a * v;
    out[idx] = v;
}

// comm-FC: out[b,a,o] = dot(cat(feat[b,a,:], mean_a feat[b,:,:]), w[a,o,:]) + bias[a,o]
template<int D, int O, bool PRELU_ON>
__global__ void comm_fc_kernel(const float* __restrict__ feat,
                               const float* __restrict__ w,
                               const float* __restrict__ bias,
                               const float* __restrict__ slope,
                               float* __restrict__ out)
{
    const int a = blockIdx.x;
    const int b = blockIdx.y;

    __shared__ __align__(16) float cat[2 * D];
    for (int i = threadIdx.x; i < D; i += blockDim.x) {
        float m = 0.f;
        #pragma unroll
        for (int aa = 0; aa < 5; ++aa) m += feat[(b * 5 + aa) * D + i];
        cat[i]     = feat[(b * 5 + a) * D + i];
        cat[D + i] = m * 0.2f;
    }
    __syncthreads();

    for (int o = threadIdx.x; o < O; o += blockDim.x) {
        const float4* wr = (const float4*)(w + ((long)(a * O) + o) * 2 * D);
        const float4* cr = (const float4*)cat;
        float acc = 0.f;
        for (int i = 0; i < 2 * D / 4; ++i) {
            float4 wv = wr[i];
            float4 cv = cr[i];
            acc += wv.x * cv.x + wv.y * cv.y + wv.z * cv.z + wv.w * cv.w;
        }
        acc += bias[a * O + o];
        if constexpr (PRELU_ON) {
            float s = slope[0];
            acc = (acc >= 0.f) ? acc : s * acc;
        }
        out[(b * 5 + a) * O + o] = acc;
    }
}

extern "C" void kernel_launch(void* const* d_in, const int* in_sizes, int n_in,
                              void* d_out, int out_size, void* d_ws, size_t ws_size,
                              hipStream_t stream)
{
    const float* x    = (const float*)d_in[0];
    const float* c0w  = (const float*)d_in[1];
    const float* c0b  = (const float*)d_in[2];
    const float* p0   = (const float*)d_in[3];
    const float* c1w  = (const float*)d_in[4];
    const float* c1b  = (const float*)d_in[5];
    const float* p1   = (const float*)d_in[6];
    const float* c2w  = (const float*)d_in[7];
    const float* c2b  = (const float*)d_in[8];
    const float* p2   = (const float*)d_in[9];
    const float* c3w  = (const float*)d_in[10];
    const float* c3b  = (const float*)d_in[11];
    const float* p3   = (const float*)d_in[12];
    const float* f1w  = (const float*)d_in[13];
    const float* f1b  = (const float*)d_in[14];
    const float* p4   = (const float*)d_in[15];
    const float* f2w  = (const float*)d_in[16];
    const float* f2b  = (const float*)d_in[17];
    const float* p5   = (const float*)d_in[18];
    const float* f3w  = (const float*)d_in[19];
    const float* f3b  = (const float*)d_in[20];

    float* ws = (float*)d_ws;
    // Region A first holds P0 (conv0 input); after conv0, P0 is dead and A is
    // reused for P2/P3/feats. P1 must coexist with both -> placed after A.
    float* P0    = ws;                       // 80*4*47*47*48 = 33,930,240 floats
    float* P1    = ws + 33930240;            // 80*32*23*23*24 = 32,501,760
    float* P2    = ws;                       // 80*32*11*11*12 =  3,717,120 (aliases dead P0)
    float* P3    = ws + 3717120;             // 80*64*4^3      =    327,680
    float* feat0 = P3 + 327680;              // 80*512
    float* feat1 = feat0 + 40960;            // 16*5*256
    float* feat2 = feat1 + 20480;            // 16*5*128

    // zero P0 (halos) + P1 (halos)
    hipMemsetAsync(ws, 0, (33930240L + 32501760L) * sizeof(float), stream);
    pad_input_kernel<<<(29160000 + 255) / 256, 256, 0, stream>>>(x, P0);

    // conv0: 4->32, k5, in padded [47][47][48], out padded [23][23][24]; PX=3
    conv_pool_kernel<4, 5, 47, 48, 106032, 21, 3, 24, 1>
        <<<dim3(13, 32, 80), dim3(256), 0, stream>>>(P0, c0w, c0b, p0, P1, 1.f / 255.f);

    // zero P2 halos (P0 now dead)
    hipMemsetAsync(P2, 0, 3717120L * sizeof(float), stream);

    // conv1: 32->32, k5, in padded [23][23][24], out padded [11][11][12]; PX=3
    conv_pool_kernel<32, 5, 23, 24, 12696, 9, 3, 12, 1>
        <<<dim3(1, 32, 80), dim3(256), 0, stream>>>(P1, c1w, c1b, p1, P2, 1.f);

    // conv2: 32->64, k4, in padded [11][11][12], out plain [4][4][4]; PX=1
    conv_pool_kernel<32, 4, 11, 12, 1452, 4, 1, 4, 0>
        <<<dim3(1, 64, 80), dim3(64), 0, stream>>>(P2, c2w, c2b, p2, P3, 1.f);

    // conv3: 64->64, k3 pad0, 4^3 -> 2^3
    conv3_kernel<<<dim3(160), dim3(256), 0, stream>>>(P3, c3w, c3b, p3, feat0);

    // comm FC stack
    comm_fc_kernel<512, 256, true>
        <<<dim3(5, 16), dim3(256), 0, stream>>>(feat0, f1w, f1b, p4, feat1);
    comm_fc_kernel<256, 128, true>
        <<<dim3(5, 16), dim3(256), 0, stream>>>(feat1, f2w, f2b, p5, feat2);
    comm_fc_kernel<128, 6, false>
        <<<dim3(5, 16), dim3(64), 0, stream>>>(feat2, f3w, f3b, nullptr, (float*)d_out);
}

// Round 6
// 3843.840 us; speedup vs baseline: 48.8574x; 1.4819x over previous
//
#include <hip/hip_runtime.h>

// ---------------------------------------------------------------------------
// CommNet round 6: conv0+conv1 as bf16 MFMA implicit GEMM using the
// HW-VERIFIED mfma_f32_16x16x32_bf16 layouts:
//   A[m=lane&15][k=(lane>>4)*8+j]   (m120)
//   B[n=lane&15][k=(lane>>4)*8+j]   (gemm_bt, m92/m97)
//   D: col(n)=lane&15, row(m)=(lane>>4)*4+reg   (m89/m91)
// Split-A hi/lo bf16 (A = hi + lo exact to 2^-17) with bf16 weights.
// R5 bug fixed: epilogue used `if (tid < 672)` with 256 threads -> only
// px 0..7 written; now strided loops.
// ---------------------------------------------------------------------------

typedef __attribute__((ext_vector_type(8)))  short bf16x8;
typedef __attribute__((ext_vector_type(4)))  short bf16x4;
typedef __attribute__((ext_vector_type(4)))  float f32x4;

__device__ __forceinline__ ushort f2bf(float f) {
    union { float f; unsigned u; } v; v.f = f;
    unsigned u = v.u;
    u += 0x7fff + ((u >> 16) & 1);          // RNE
    return (ushort)(u >> 16);
}
__device__ __forceinline__ float bf2f(ushort h) {
    union { unsigned u; float f; } v; v.u = ((unsigned)h) << 16;
    return v.f;
}

// ---- prep: x [80][4][45^3] fp32 -> hi0/lo0 NDHWC padded [80][47][47][48][4]
__global__ void pad_input_kernel(const float* __restrict__ x,
                                 ushort* __restrict__ hi, ushort* __restrict__ lo)
{
    int t = blockIdx.x * 256 + threadIdx.x;
    const int TOT = 80 * 45 * 45 * 45;
    if (t >= TOT) return;
    int xi = t % 45, r = t / 45;
    int y = r % 45; r /= 45;
    int z = r % 45; int n = r / 45;
    int ib = ((n * 4) * 91125) + z * 2025 + y * 45 + xi;
    int ob = (((n * 47 + z + 1) * 47 + y + 1) * 48 + xi + 1) * 4;
    ushort h4[4], l4[4];
    #pragma unroll
    for (int ic = 0; ic < 4; ++ic) {
        float v = x[ib + ic * 91125] * (1.f / 255.f);
        ushort h = f2bf(v);
        h4[ic] = h; l4[ic] = f2bf(v - bf2f(h));
    }
    *(ushort4*)(hi + ob) = *(ushort4*)h4;
    *(ushort4*)(lo + ob) = *(ushort4*)l4;
}

// ---- pack conv0 weights [32][4][5][5][5] -> Bp0[19 s][2 ot][64 lane][8 j]
// k = ((kz*5+ky)*6+kx)*4 + ic  (kx in [0,6), kx==5 zero; K=600 pad 608)
__global__ void pack_w0(const float* __restrict__ w, ushort* __restrict__ Bp,
                        int4* __restrict__ Dt)
{
    int t = blockIdx.x * 256 + threadIdx.x;
    if (t < 19 * 2 * 64 * 8) {
        int j = t & 7, l = (t >> 3) & 63, ot = (t >> 9) & 1, s = t >> 10;
        int oc = ot * 16 + (l & 15);
        int k = 32 * s + ((l >> 4) << 3) + j;
        float v = 0.f;
        if (k < 600) {
            int ic = k & 3, t6 = k >> 2;
            int kx = t6 % 6, q = t6 / 6, ky = q % 5, kz = q / 5;
            if (kx < 5) v = w[(oc * 4 + ic) * 125 + kz * 25 + ky * 5 + kx];
        }
        Bp[t] = f2bf(v);
    }
    if (t < 19) {
        int dd[4];
        #pragma unroll
        for (int q = 0; q < 4; ++q) {
            int k = 32 * t + 8 * q;
            if (k < 600) {
                int t6 = k >> 2;
                int kx = t6 % 6, qq = t6 / 6;
                dd[q] = (((qq / 5) * 47 + (qq % 5)) * 48 + kx) * 4;
            } else dd[q] = 0;
        }
        int4 d; d.x = dd[0]; d.y = dd[1]; d.z = dd[2]; d.w = dd[3];
        Dt[t] = d;
    }
}

// ---- pack conv1 weights [32][32][5][5][5] -> Bp1[125 s][2 ot][64][8]
// step s = tap, k = s*32 + ic (ic = q*8+j)
__global__ void pack_w1(const float* __restrict__ w, ushort* __restrict__ Bp,
                        int* __restrict__ Dt)
{
    int t = blockIdx.x * 256 + threadIdx.x;
    if (t < 125 * 2 * 64 * 8) {
        int j = t & 7, l = (t >> 3) & 63, ot = (t >> 9) & 1, s = t >> 10;
        int oc = ot * 16 + (l & 15);
        int ic = ((l >> 4) << 3) + j;
        Bp[t] = f2bf(w[(oc * 32 + ic) * 125 + s]);
    }
    if (t < 125) {
        int kz = t / 25, ky = (t / 5) % 5, kx = t % 5;
        Dt[t] = ((kz * 23 + ky) * 24 + kx) * 32;
    }
}

// ---- conv0 MFMA: in hi0/lo0 [80][47][47][48][4] -> out hi1/lo1 [80][23][23][24][32]
__global__ __launch_bounds__(256)
void conv0_mfma(const ushort* __restrict__ hi0, const ushort* __restrict__ lo0,
                const ushort* __restrict__ Bp, const int4* __restrict__ Dt,
                const float* __restrict__ bias, const float* __restrict__ slope,
                ushort* __restrict__ hi1, ushort* __restrict__ lo1)
{
    const int n  = blockIdx.z;
    const int pz = blockIdx.x / 21, py = blockIdx.x % 21;
    const int tid = threadIdx.x, lane = tid & 63, w = tid >> 6;
    const int dz = w >> 1, dy = w & 1;
    const int q = lane >> 4, l15 = lane & 15;

    __shared__ __align__(16) ushort Bsh[19 * 2 * 64 * 8];   // 38912 B
    __shared__ float pool[4][21][32];
    for (int i = tid; i < 19 * 2 * 64; i += 256)
        ((bf16x8*)Bsh)[i] = ((const bf16x8*)Bp)[i];
    __syncthreads();

    const int z0 = 2 * pz + dz, y0 = 2 * py + dy;
    const float sl = slope[0];

    for (int xt = 0; xt < 3; ++xt) {
        int x = xt * 16 + l15;
        int xr = x > 41 ? 41 : x;
        int abase = (((n * 47 + z0) * 47 + y0) * 48 + xr) * 4;
        f32x4 acc0 = {}, acc1 = {};
        for (int s = 0; s < 19; ++s) {
            int4 dd = Dt[s];
            int delta = q == 0 ? dd.x : q == 1 ? dd.y : q == 2 ? dd.z : dd.w;
            int idx = abase + delta;
            bf16x4 h0 = *(const bf16x4*)(hi0 + idx);
            bf16x4 h1 = *(const bf16x4*)(hi0 + idx + 4);
            bf16x4 l0 = *(const bf16x4*)(lo0 + idx);
            bf16x4 l1 = *(const bf16x4*)(lo0 + idx + 4);
            bf16x8 ah, al;
            ah[0]=h0[0]; ah[1]=h0[1]; ah[2]=h0[2]; ah[3]=h0[3];
            ah[4]=h1[0]; ah[5]=h1[1]; ah[6]=h1[2]; ah[7]=h1[3];
            al[0]=l0[0]; al[1]=l0[1]; al[2]=l0[2]; al[3]=l0[3];
            al[4]=l1[0]; al[5]=l1[1]; al[6]=l1[2]; al[7]=l1[3];
            const bf16x8* bs = (const bf16x8*)&Bsh[((s * 2) * 64 + lane) * 8];
            bf16x8 b0 = bs[0];
            bf16x8 b1 = bs[64];
            acc0 = __builtin_amdgcn_mfma_f32_16x16x32_bf16(ah, b0, acc0, 0, 0, 0);
            acc0 = __builtin_amdgcn_mfma_f32_16x16x32_bf16(al, b0, acc0, 0, 0, 0);
            acc1 = __builtin_amdgcn_mfma_f32_16x16x32_bf16(ah, b1, acc1, 0, 0, 0);
            acc1 = __builtin_amdgcn_mfma_f32_16x16x32_bf16(al, b1, acc1, 0, 0, 0);
        }
        // D rows m = 4q+reg; pool pairs (4q,4q+1)->px 2q, (4q+2,4q+3)->px 2q+1
        int pxe = xt * 8 + 2 * q, pxo = pxe + 1;
        float pe0 = fmaxf(acc0[0], acc0[1]), po0 = fmaxf(acc0[2], acc0[3]);
        float pe1 = fmaxf(acc1[0], acc1[1]), po1 = fmaxf(acc1[2], acc1[3]);
        if (pxe < 21) { pool[w][pxe][l15] = pe0; pool[w][pxe][16 + l15] = pe1; }
        if (pxo < 21) { pool[w][pxo][l15] = po0; pool[w][pxo][16 + l15] = po1; }
    }
    __syncthreads();

    for (int t2 = tid; t2 < 672; t2 += 256) {
        int oc = t2 & 31, px = t2 >> 5;
        float v = fmaxf(fmaxf(pool[0][px][oc], pool[1][px][oc]),
                        fmaxf(pool[2][px][oc], pool[3][px][oc]));
        v += bias[oc];
        v = (v >= 0.f) ? v : sl * v;
        int o = (((n * 23 + pz + 1) * 23 + py + 1) * 24 + px + 1) * 32 + oc;
        ushort h = f2bf(v);
        hi1[o] = h; lo1[o] = f2bf(v - bf2f(h));
    }
}

// ---- conv1 MFMA: in hi1/lo1 [80][23][23][24][32] -> P2 fp32 NCDHW padded
// [80][32][11][11][12] (interior at +1)
__global__ __launch_bounds__(256)
void conv1_mfma(const ushort* __restrict__ hi1, const ushort* __restrict__ lo1,
                const ushort* __restrict__ Bp, const int* __restrict__ Dt,
                const float* __restrict__ bias, const float* __restrict__ slope,
                float* __restrict__ P2)
{
    const int n  = blockIdx.z;
    const int pz = blockIdx.x / 9, py = blockIdx.x % 9;
    const int tid = threadIdx.x, lane = tid & 63, w = tid >> 6;
    const int dz = w >> 1, dy = w & 1;
    const int q = lane >> 4, l15 = lane & 15;

    __shared__ float pool[4][9][32];
    const int z0 = 2 * pz + dz, y0 = 2 * py + dy;

    for (int xt = 0; xt < 2; ++xt) {
        int x = xt * 16 + l15;
        int xr = x > 17 ? 17 : x;
        int abase = ((((n * 23 + z0) * 23 + y0) * 24 + xr) << 5) + q * 8;
        f32x4 acc0 = {}, acc1 = {};
        for (int s = 0; s < 125; ++s) {
            int off = Dt[s];
            bf16x8 ah = *(const bf16x8*)(hi1 + abase + off);
            bf16x8 al = *(const bf16x8*)(lo1 + abase + off);
            const bf16x8* bp = (const bf16x8*)Bp + (s * 2) * 64 + lane;
            bf16x8 b0 = bp[0];
            bf16x8 b1 = bp[64];
            acc0 = __builtin_amdgcn_mfma_f32_16x16x32_bf16(ah, b0, acc0, 0, 0, 0);
            acc0 = __builtin_amdgcn_mfma_f32_16x16x32_bf16(al, b0, acc0, 0, 0, 0);
            acc1 = __builtin_amdgcn_mfma_f32_16x16x32_bf16(ah, b1, acc1, 0, 0, 0);
            acc1 = __builtin_amdgcn_mfma_f32_16x16x32_bf16(al, b1, acc1, 0, 0, 0);
        }
        int pxe = xt * 8 + 2 * q, pxo = pxe + 1;
        float pe0 = fmaxf(acc0[0], acc0[1]), po0 = fmaxf(acc0[2], acc0[3]);
        float pe1 = fmaxf(acc1[0], acc1[1]), po1 = fmaxf(acc1[2], acc1[3]);
        if (pxe < 9) { pool[w][pxe][l15] = pe0; pool[w][pxe][16 + l15] = pe1; }
        if (pxo < 9) { pool[w][pxo][l15] = po0; pool[w][pxo][16 + l15] = po1; }
    }
    __syncthreads();

    for (int t2 = tid; t2 < 288; t2 += 256) {
        int oc = t2 & 31, px = t2 >> 5;
        float v = fmaxf(fmaxf(pool[0][px][oc], pool[1][px][oc]),
                        fmaxf(pool[2][px][oc], pool[3][px][oc]));
        v += bias[oc];
        float s0 = slope[0];
        v = (v >= 0.f) ? v : s0 * v;
        P2[(long)n * 32 * 11 * 11 * 12 +
           ((oc * 11 + pz + 1) * 11 + py + 1) * 12 + px + 1] = v;
    }
}

// ---- conv2 (fp32 direct, R4-verified) ----
template<int CIN, int K, int SY, int SXS, int ICS, int SPOOL, int PX,
         int OXS, int OPAD>
__global__ __launch_bounds__(256, 2)
void conv_pool_kernel(const float* __restrict__ in,
                      const float* __restrict__ w,
                      const float* __restrict__ bias,
                      const float* __restrict__ slope,
                      float* __restrict__ out,
                      float scale)
{
    constexpr int NX  = 2 * PX;
    constexpr int LX  = NX + K - 1;
    constexpr int LX2 = (LX + 1) / 2;
    constexpr int XT  = SPOOL / PX;
    constexpr int OD  = SPOOL + 2 * OPAD;

    const int oc   = blockIdx.y;
    const int n    = blockIdx.z;
    const int COUT = gridDim.y;

    int idx = blockIdx.x * blockDim.x + threadIdx.x;
    const int POS = XT * SPOOL * SPOOL;
    if (idx >= POS) return;

    int xt  = idx % XT;
    int py  = (idx / XT) % SPOOL;
    int pz  = idx / (XT * SPOOL);
    int px0 = xt * PX;

    const float* inb = in + (long)n * CIN * ICS + (2 * pz * SY + 2 * py) * SXS + 2 * px0;
    const float* wb  = w + (long)oc * CIN * K * K * K;

    float acc[2][2][NX] = {};

    #pragma unroll 1
    for (int ic = 0; ic < CIN; ++ic) {
        const float* inc = inb + (long)ic * ICS;
        const float* wic = wb + ic * K * K * K;
        #pragma unroll
        for (int tz = 0; tz < K + 1; ++tz) {
            #pragma unroll
            for (int ty = 0; ty < K + 1; ++ty) {
                const float2* rp = (const float2*)(inc + (tz * SY + ty) * SXS);
                float row[LX2 * 2];
                #pragma unroll
                for (int i = 0; i < LX2; ++i) {
                    float2 t = rp[i];
                    row[2 * i] = t.x; row[2 * i + 1] = t.y;
                }
                #pragma unroll
                for (int dzz = 0; dzz < 2; ++dzz) {
                    if (tz - dzz < 0 || tz - dzz >= K) continue;
                    #pragma unroll
                    for (int dyy = 0; dyy < 2; ++dyy) {
                        if (ty - dyy < 0 || ty - dyy >= K) continue;
                        const float* wrow = wic + ((tz - dzz) * K + (ty - dyy)) * K;
                        #pragma unroll
                        for (int kx = 0; kx < K; ++kx) {
                            float wv = wrow[kx];
                            #pragma unroll
                            for (int dx = 0; dx < NX; ++dx)
                                acc[dzz][dyy][dx] += wv * row[kx + dx];
                        }
                    }
                }
            }
        }
    }

    float b = bias[oc];
    float a = slope[0];
    long ob = ((long)n * COUT + oc) * (OD * OD * OXS)
            + (long)(pz + OPAD) * (OD * OXS) + (py + OPAD) * OXS + OPAD + px0;
    #pragma unroll
    for (int j = 0; j < PX; ++j) {
        float m = -3.4e38f;
        #pragma unroll
        for (int dzz = 0; dzz < 2; ++dzz)
            #pragma unroll
            for (int dyy = 0; dyy < 2; ++dyy)
                #pragma unroll
                for (int dx = 0; dx < 2; ++dx) {
                    float v = acc[dzz][dyy][2 * j + dx] * scale + b;
                    v = (v >= 0.f) ? v : a * v;
                    m = fmaxf(m, v);
                }
        out[ob + j] = m;
    }
}

// ---- conv3 (fp32 direct) ----
__global__ void conv3_kernel(const float* __restrict__ in,
                             const float* __restrict__ w,
                             const float* __restrict__ bias,
                             const float* __restrict__ slope,
                             float* __restrict__ out)
{
    int idx = blockIdx.x * blockDim.x + threadIdx.x;
    const int TOTAL = 80 * 64 * 8;
    if (idx >= TOTAL) return;
    int p  = idx & 7;
    int oc = (idx >> 3) & 63;
    int n  = idx >> 9;
    int ox = p & 1, oy = (p >> 1) & 1, oz = p >> 2;

    const float* inb = in + (long)n * 64 * 64;
    const float* wb  = w + (long)oc * 64 * 27;

    float acc = 0.f;
    for (int ic = 0; ic < 64; ++ic) {
        const float* inc = inb + ic * 64;
        const float* wc  = wb + ic * 27;
        #pragma unroll
        for (int kz = 0; kz < 3; ++kz)
            #pragma unroll
            for (int ky = 0; ky < 3; ++ky)
                #pragma unroll
                for (int kx = 0; kx < 3; ++kx)
                    acc += wc[(kz * 3 + ky) * 3 + kx] *
                           inc[((oz + kz) * 4 + (oy + ky)) * 4 + (ox + kx)];
    }
    float v = acc + bias[oc];
    float a = slope[0];
    v = (v >= 0.f) ? v : a * v;
    out[idx] = v;
}

// ---- comm-FC ----
template<int D, int O, bool PRELU_ON>
__global__ void comm_fc_kernel(const float* __restrict__ feat,
                               const float* __restrict__ w,
                               const float* __restrict__ bias,
                               const float* __restrict__ slope,
                               float* __restrict__ out)
{
    const int a = blockIdx.x;
    const int b = blockIdx.y;

    __shared__ __align__(16) float cat[2 * D];
    for (int i = threadIdx.x; i < D; i += blockDim.x) {
        float m = 0.f;
        #pragma unroll
        for (int aa = 0; aa < 5; ++aa) m += feat[(b * 5 + aa) * D + i];
        cat[i]     = feat[(b * 5 + a) * D + i];
        cat[D + i] = m * 0.2f;
    }
    __syncthreads();

    for (int o = threadIdx.x; o < O; o += blockDim.x) {
        const float4* wr = (const float4*)(w + ((long)(a * O) + o) * 2 * D);
        const float4* cr = (const float4*)cat;
        float acc = 0.f;
        for (int i = 0; i < 2 * D / 4; ++i) {
            float4 wv = wr[i];
            float4 cv = cr[i];
            acc += wv.x * cv.x + wv.y * cv.y + wv.z * cv.z + wv.w * cv.w;
        }
        acc += bias[a * O + o];
        if constexpr (PRELU_ON) {
            float s = slope[0];
            acc = (acc >= 0.f) ? acc : s * acc;
        }
        out[(b * 5 + a) * O + o] = acc;
    }
}

extern "C" void kernel_launch(void* const* d_in, const int* in_sizes, int n_in,
                              void* d_out, int out_size, void* d_ws, size_t ws_size,
                              hipStream_t stream)
{
    const float* x    = (const float*)d_in[0];
    const float* c0w  = (const float*)d_in[1];
    const float* c0b  = (const float*)d_in[2];
    const float* p0   = (const float*)d_in[3];
    const float* c1w  = (const float*)d_in[4];
    const float* c1b  = (const float*)d_in[5];
    const float* p1   = (const float*)d_in[6];
    const float* c2w  = (const float*)d_in[7];
    const float* c2b  = (const float*)d_in[8];
    const float* p2   = (const float*)d_in[9];
    const float* c3w  = (const float*)d_in[10];
    const float* c3b  = (const float*)d_in[11];
    const float* p3   = (const float*)d_in[12];
    const float* f1w  = (const float*)d_in[13];
    const float* f1b  = (const float*)d_in[14];
    const float* p4   = (const float*)d_in[15];
    const float* f2w  = (const float*)d_in[16];
    const float* f2b  = (const float*)d_in[17];
    const float* p5   = (const float*)d_in[18];
    const float* f3w  = (const float*)d_in[19];
    const float* f3b  = (const float*)d_in[20];

    char* ws = (char*)d_ws;
    ushort* hi0  = (ushort*)(ws);                         // 33,930,240 el
    ushort* lo0  = (ushort*)(ws + 67860480);
    ushort* hi1  = (ushort*)(ws + 135720960);             // 32,501,760 el
    ushort* lo1  = (ushort*)(ws + 200724480);
    float*  P2   = (float*) (ws + 265728000);             //  3,717,120 el
    float*  P3   = (float*) (ws + 280596480);             //    327,680 el
    float*  feat0= (float*) (ws + 281907200);
    float*  feat1= (float*) (ws + 282071040);
    float*  feat2= (float*) (ws + 282152960);
    ushort* Bp0  = (ushort*)(ws + 282193920);             // 19,456 el
    ushort* Bp1  = (ushort*)(ws + 282232832);             // 128,000 el
    int4*   Dt0  = (int4*)  (ws + 282488832);             // 19
    int*    Dt1  = (int*)   (ws + 282489152);             // 125

    // zero halos of hi0/lo0/hi1/lo1 + all of P2
    hipMemsetAsync(ws, 0, 280596480, stream);

    pack_w0<<<76, 256, 0, stream>>>(c0w, Bp0, Dt0);
    pack_w1<<<500, 256, 0, stream>>>(c1w, Bp1, Dt1);
    pad_input_kernel<<<(7290000 + 255) / 256, 256, 0, stream>>>(x, hi0, lo0);

    conv0_mfma<<<dim3(441, 1, 80), 256, 0, stream>>>(hi0, lo0, Bp0, Dt0,
                                                     c0b, p0, hi1, lo1);
    conv1_mfma<<<dim3(81, 1, 80), 256, 0, stream>>>(hi1, lo1, Bp1, Dt1,
                                                    c1b, p1, P2);

    conv_pool_kernel<32, 4, 11, 12, 1452, 4, 1, 4, 0>
        <<<dim3(1, 64, 80), dim3(64), 0, stream>>>(P2, c2w, c2b, p2, P3, 1.f);

    conv3_kernel<<<dim3(160), dim3(256), 0, stream>>>(P3, c3w, c3b, p3, feat0);

    comm_fc_kernel<512, 256, true>
        <<<dim3(5, 16), dim3(256), 0, stream>>>(feat0, f1w, f1b, p4, feat1);
    comm_fc_kernel<256, 128, true>
        <<<dim3(5, 16), dim3(256), 0, stream>>>(feat1, f2w, f2b, p5, feat2);
    comm_fc_kernel<128, 6, false>
        <<<dim3(5, 16), dim3(64), 0, stream>>>(feat2, f3w, f3b, nullptr, (float*)d_out);
}

// Round 7
// 2498.486 us; speedup vs baseline: 75.1655x; 1.5385x over previous
//
#include <hip/hip_runtime.h>

// ---------------------------------------------------------------------------
// CommNet round 7: conv0/conv1 MFMA implicit GEMM, latency-tuned.
//  R6 counters: MfmaUtil 9.9 / VALUBusy 11.6 / occ 23% -> latency-bound.
//  - B read from global (L1/L2-hot), no LDS staging -> LDS = pool only
//  - hi/lo interleaved per x-unit -> aligned 16B A-loads, half the loads
//  - xt fused into K-loop -> 6 indep acc chains, ~8 loads in flight/wave
// Layouts (HW-verified, m89/m91/m92/m120):
//   A[m=lane&15][k=(lane>>4)*8+j], B[n=lane&15][k=(lane>>4)*8+j]
//   D: col(n)=lane&15, row(m)=(lane>>4)*4+reg
// ---------------------------------------------------------------------------

typedef __attribute__((ext_vector_type(8)))  short bf16x8;
typedef __attribute__((ext_vector_type(4)))  float f32x4;

__device__ __forceinline__ ushort f2bf(float f) {
    union { float f; unsigned u; } v; v.f = f;
    unsigned u = v.u;
    u += 0x7fff + ((u >> 16) & 1);          // RNE
    return (ushort)(u >> 16);
}
__device__ __forceinline__ float bf2f(ushort h) {
    union { unsigned u; float f; } v; v.u = ((unsigned)h) << 16;
    return v.f;
}

// ---- prep: x [80][4][45^3] fp32 -> hil0 padded [80][47][47][48][8]
// per x-unit: [0..3]=hi(ic0..3), [4..7]=lo(ic0..3)
__global__ void pad_input_kernel(const float* __restrict__ x,
                                 ushort* __restrict__ hil)
{
    int t = blockIdx.x * 256 + threadIdx.x;
    const int TOT = 80 * 45 * 45 * 45;
    if (t >= TOT) return;
    int xi = t % 45, r = t / 45;
    int y = r % 45; r /= 45;
    int z = r % 45; int n = r / 45;
    int ib = ((n * 4) * 91125) + z * 2025 + y * 45 + xi;
    int ob = (((n * 47 + z + 1) * 47 + y + 1) * 48 + xi + 1) * 8;
    ushort u[8];
    #pragma unroll
    for (int ic = 0; ic < 4; ++ic) {
        float v = x[ib + ic * 91125] * (1.f / 255.f);
        ushort h = f2bf(v);
        u[ic] = h; u[4 + ic] = f2bf(v - bf2f(h));
    }
    *(ulonglong2*)(hil + ob) = *(ulonglong2*)u;
}

// ---- pack conv0 weights [32][4][5][5][5] -> Bp0[19 s][2 ot][64 lane][8 j]
// k = ((kz*5+ky)*6+kx)*4 + ic  (kx in [0,6), kx==5 zero; K=600 pad 608)
__global__ void pack_w0(const float* __restrict__ w, ushort* __restrict__ Bp,
                        int4* __restrict__ Dt)
{
    int t = blockIdx.x * 256 + threadIdx.x;
    if (t < 19 * 2 * 64 * 8) {
        int j = t & 7, l = (t >> 3) & 63, ot = (t >> 9) & 1, s = t >> 10;
        int oc = ot * 16 + (l & 15);
        int k = 32 * s + ((l >> 4) << 3) + j;
        float v = 0.f;
        if (k < 600) {
            int ic = k & 3, t6 = k >> 2;
            int kx = t6 % 6, q = t6 / 6, ky = q % 5, kz = q / 5;
            if (kx < 5) v = w[(oc * 4 + ic) * 125 + kz * 25 + ky * 5 + kx];
        }
        Bp[t] = f2bf(v);
    }
    if (t < 19) {
        int dd[4];
        #pragma unroll
        for (int q = 0; q < 4; ++q) {
            int k = 32 * t + 8 * q;
            if (k < 600) {
                int t6 = k >> 2;
                int kx = t6 % 6, qq = t6 / 6;
                dd[q] = (((qq / 5) * 47 + (qq % 5)) * 48 + kx) * 8;  // x-unit=8
            } else dd[q] = 0;
        }
        int4 d; d.x = dd[0]; d.y = dd[1]; d.z = dd[2]; d.w = dd[3];
        Dt[t] = d;
    }
}

// ---- pack conv1 weights [32][32][5][5][5] -> Bp1[125 s][2 ot][64][8]
__global__ void pack_w1(const float* __restrict__ w, ushort* __restrict__ Bp,
                        int* __restrict__ Dt)
{
    int t = blockIdx.x * 256 + threadIdx.x;
    if (t < 125 * 2 * 64 * 8) {
        int j = t & 7, l = (t >> 3) & 63, ot = (t >> 9) & 1, s = t >> 10;
        int oc = ot * 16 + (l & 15);
        int ic = ((l >> 4) << 3) + j;
        Bp[t] = f2bf(w[(oc * 32 + ic) * 125 + s]);
    }
    if (t < 125) {
        int kz = t / 25, ky = (t / 5) % 5, kx = t % 5;
        Dt[t] = ((kz * 23 + ky) * 24 + kx) * 64;                     // x-unit=64
    }
}

// ---- conv0 MFMA: hil0 [80][47][47][48][8] -> hil1 [80][23][23][24][64]
// hil1 per x-unit: [0..31]=hi(oc), [32..63]=lo(oc)
__global__ __launch_bounds__(256)
void conv0_mfma(const ushort* __restrict__ hil0,
                const ushort* __restrict__ Bp, const int4* __restrict__ Dt,
                const float* __restrict__ bias, const float* __restrict__ slope,
                ushort* __restrict__ hil1)
{
    const int n  = blockIdx.z;
    const int pz = blockIdx.x / 21, py = blockIdx.x % 21;
    const int tid = threadIdx.x, lane = tid & 63, w = tid >> 6;
    const int dz = w >> 1, dy = w & 1;
    const int q = lane >> 4, l15 = lane & 15;

    __shared__ float pool[4][21][32];

    const int z0 = 2 * pz + dz, y0 = 2 * py + dy;
    const float sl = slope[0];

    int ab[3];
    #pragma unroll
    for (int xt = 0; xt < 3; ++xt) {
        int x = xt * 16 + l15;
        int xr = x > 41 ? 41 : x;
        ab[xt] = (((n * 47 + z0) * 47 + y0) * 48 + xr) * 8;
    }

    f32x4 acc[3][2] = {};
    const bf16x8* Bv = (const bf16x8*)Bp;

    #pragma unroll 2
    for (int s = 0; s < 19; ++s) {
        int4 dd = Dt[s];
        int delta = q == 0 ? dd.x : q == 1 ? dd.y : q == 2 ? dd.z : dd.w;
        bf16x8 b0 = Bv[(2 * s) * 64 + lane];
        bf16x8 b1 = Bv[(2 * s + 1) * 64 + lane];
        #pragma unroll
        for (int xt = 0; xt < 3; ++xt) {
            const bf16x8* ap = (const bf16x8*)(hil0 + ab[xt] + delta);
            bf16x8 u0 = ap[0];
            bf16x8 u1 = ap[1];
            bf16x8 ah = {u0[0], u0[1], u0[2], u0[3], u1[0], u1[1], u1[2], u1[3]};
            bf16x8 al = {u0[4], u0[5], u0[6], u0[7], u1[4], u1[5], u1[6], u1[7]};
            acc[xt][0] = __builtin_amdgcn_mfma_f32_16x16x32_bf16(ah, b0, acc[xt][0], 0, 0, 0);
            acc[xt][0] = __builtin_amdgcn_mfma_f32_16x16x32_bf16(al, b0, acc[xt][0], 0, 0, 0);
            acc[xt][1] = __builtin_amdgcn_mfma_f32_16x16x32_bf16(ah, b1, acc[xt][1], 0, 0, 0);
            acc[xt][1] = __builtin_amdgcn_mfma_f32_16x16x32_bf16(al, b1, acc[xt][1], 0, 0, 0);
        }
    }

    #pragma unroll
    for (int xt = 0; xt < 3; ++xt) {
        int pxe = xt * 8 + 2 * q, pxo = pxe + 1;
        float pe0 = fmaxf(acc[xt][0][0], acc[xt][0][1]);
        float po0 = fmaxf(acc[xt][0][2], acc[xt][0][3]);
        float pe1 = fmaxf(acc[xt][1][0], acc[xt][1][1]);
        float po1 = fmaxf(acc[xt][1][2], acc[xt][1][3]);
        if (pxe < 21) { pool[w][pxe][l15] = pe0; pool[w][pxe][16 + l15] = pe1; }
        if (pxo < 21) { pool[w][pxo][l15] = po0; pool[w][pxo][16 + l15] = po1; }
    }
    __syncthreads();

    for (int t2 = tid; t2 < 672; t2 += 256) {
        int oc = t2 & 31, px = t2 >> 5;
        float v = fmaxf(fmaxf(pool[0][px][oc], pool[1][px][oc]),
                        fmaxf(pool[2][px][oc], pool[3][px][oc]));
        v += bias[oc];
        v = (v >= 0.f) ? v : sl * v;
        int o = (((n * 23 + pz + 1) * 23 + py + 1) * 24 + px + 1) * 64 + oc;
        ushort h = f2bf(v);
        hil1[o] = h; hil1[o + 32] = f2bf(v - bf2f(h));
    }
}

// ---- conv1 MFMA: hil1 [80][23][23][24][64] -> P2 fp32 NCDHW padded
// [80][32][11][11][12] (interior at +1)
__global__ __launch_bounds__(256)
void conv1_mfma(const ushort* __restrict__ hil1,
                const ushort* __restrict__ Bp, const int* __restrict__ Dt,
                const float* __restrict__ bias, const float* __restrict__ slope,
                float* __restrict__ P2)
{
    const int n  = blockIdx.z;
    const int pz = blockIdx.x / 9, py = blockIdx.x % 9;
    const int tid = threadIdx.x, lane = tid & 63, w = tid >> 6;
    const int dz = w >> 1, dy = w & 1;
    const int q = lane >> 4, l15 = lane & 15;

    __shared__ float pool[4][9][32];
    const int z0 = 2 * pz + dz, y0 = 2 * py + dy;

    int ab[2];
    #pragma unroll
    for (int xt = 0; xt < 2; ++xt) {
        int x = xt * 16 + l15;
        int xr = x > 17 ? 17 : x;
        ab[xt] = ((((n * 23 + z0) * 23 + y0) * 24 + xr) << 6) + q * 8;
    }

    f32x4 acc[2][2] = {};
    const bf16x8* Bv = (const bf16x8*)Bp;

    #pragma unroll 2
    for (int s = 0; s < 125; ++s) {
        int off = Dt[s];
        bf16x8 b0 = Bv[(2 * s) * 64 + lane];
        bf16x8 b1 = Bv[(2 * s + 1) * 64 + lane];
        #pragma unroll
        for (int xt = 0; xt < 2; ++xt) {
            bf16x8 ah = *(const bf16x8*)(hil1 + ab[xt] + off);
            bf16x8 al = *(const bf16x8*)(hil1 + ab[xt] + off + 32);
            acc[xt][0] = __builtin_amdgcn_mfma_f32_16x16x32_bf16(ah, b0, acc[xt][0], 0, 0, 0);
            acc[xt][0] = __builtin_amdgcn_mfma_f32_16x16x32_bf16(al, b0, acc[xt][0], 0, 0, 0);
            acc[xt][1] = __builtin_amdgcn_mfma_f32_16x16x32_bf16(ah, b1, acc[xt][1], 0, 0, 0);
            acc[xt][1] = __builtin_amdgcn_mfma_f32_16x16x32_bf16(al, b1, acc[xt][1], 0, 0, 0);
        }
    }

    #pragma unroll
    for (int xt = 0; xt < 2; ++xt) {
        int pxe = xt * 8 + 2 * q, pxo = pxe + 1;
        float pe0 = fmaxf(acc[xt][0][0], acc[xt][0][1]);
        float po0 = fmaxf(acc[xt][0][2], acc[xt][0][3]);
        float pe1 = fmaxf(acc[xt][1][0], acc[xt][1][1]);
        float po1 = fmaxf(acc[xt][1][2], acc[xt][1][3]);
        if (pxe < 9) { pool[w][pxe][l15] = pe0; pool[w][pxe][16 + l15] = pe1; }
        if (pxo < 9) { pool[w][pxo][l15] = po0; pool[w][pxo][16 + l15] = po1; }
    }
    __syncthreads();

    for (int t2 = tid; t2 < 288; t2 += 256) {
        int oc = t2 & 31, px = t2 >> 5;
        float v = fmaxf(fmaxf(pool[0][px][oc], pool[1][px][oc]),
                        fmaxf(pool[2][px][oc], pool[3][px][oc]));
        v += bias[oc];
        float s0 = slope[0];
        v = (v >= 0.f) ? v : s0 * v;
        P2[(long)n * 32 * 11 * 11 * 12 +
           ((oc * 11 + pz + 1) * 11 + py + 1) * 12 + px + 1] = v;
    }
}

// ---- conv2 (fp32 direct, R4-verified) ----
template<int CIN, int K, int SY, int SXS, int ICS, int SPOOL, int PX,
         int OXS, int OPAD>
__global__ __launch_bounds__(256, 2)
void conv_pool_kernel(const float* __restrict__ in,
                      const float* __restrict__ w,
                      const float* __restrict__ bias,
                      const float* __restrict__ slope,
                      float* __restrict__ out,
                      float scale)
{
    constexpr int NX  = 2 * PX;
    constexpr int LX  = NX + K - 1;
    constexpr int LX2 = (LX + 1) / 2;
    constexpr int XT  = SPOOL / PX;
    constexpr int OD  = SPOOL + 2 * OPAD;

    const int oc   = blockIdx.y;
    const int n    = blockIdx.z;
    const int COUT = gridDim.y;

    int idx = blockIdx.x * blockDim.x + threadIdx.x;
    const int POS = XT * SPOOL * SPOOL;
    if (idx >= POS) return;

    int xt  = idx % XT;
    int py  = (idx / XT) % SPOOL;
    int pz  = idx / (XT * SPOOL);
    int px0 = xt * PX;

    const float* inb = in + (long)n * CIN * ICS + (2 * pz * SY + 2 * py) * SXS + 2 * px0;
    const float* wb  = w + (long)oc * CIN * K * K * K;

    float acc[2][2][NX] = {};

    #pragma unroll 1
    for (int ic = 0; ic < CIN; ++ic) {
        const float* inc = inb + (long)ic * ICS;
        const float* wic = wb + ic * K * K * K;
        #pragma unroll
        for (int tz = 0; tz < K + 1; ++tz) {
            #pragma unroll
            for (int ty = 0; ty < K + 1; ++ty) {
                const float2* rp = (const float2*)(inc + (tz * SY + ty) * SXS);
                float row[LX2 * 2];
                #pragma unroll
                for (int i = 0; i < LX2; ++i) {
                    float2 t = rp[i];
                    row[2 * i] = t.x; row[2 * i + 1] = t.y;
                }
                #pragma unroll
                for (int dzz = 0; dzz < 2; ++dzz) {
                    if (tz - dzz < 0 || tz - dzz >= K) continue;
                    #pragma unroll
                    for (int dyy = 0; dyy < 2; ++dyy) {
                        if (ty - dyy < 0 || ty - dyy >= K) continue;
                        const float* wrow = wic + ((tz - dzz) * K + (ty - dyy)) * K;
                        #pragma unroll
                        for (int kx = 0; kx < K; ++kx) {
                            float wv = wrow[kx];
                            #pragma unroll
                            for (int dx = 0; dx < NX; ++dx)
                                acc[dzz][dyy][dx] += wv * row[kx + dx];
                        }
                    }
                }
            }
        }
    }

    float b = bias[oc];
    float a = slope[0];
    long ob = ((long)n * COUT + oc) * (OD * OD * OXS)
            + (long)(pz + OPAD) * (OD * OXS) + (py + OPAD) * OXS + OPAD + px0;
    #pragma unroll
    for (int j = 0; j < PX; ++j) {
        float m = -3.4e38f;
        #pragma unroll
        for (int dzz = 0; dzz < 2; ++dzz)
            #pragma unroll
            for (int dyy = 0; dyy < 2; ++dyy)
                #pragma unroll
                for (int dx = 0; dx < 2; ++dx) {
                    float v = acc[dzz][dyy][2 * j + dx] * scale + b;
                    v = (v >= 0.f) ? v : a * v;
                    m = fmaxf(m, v);
                }
        out[ob + j] = m;
    }
}

// ---- conv3 (fp32 direct) ----
__global__ void conv3_kernel(const float* __restrict__ in,
                             const float* __restrict__ w,
                             const float* __restrict__ bias,
                             const float* __restrict__ slope,
                             float* __restrict__ out)
{
    int idx = blockIdx.x * blockDim.x + threadIdx.x;
    const int TOTAL = 80 * 64 * 8;
    if (idx >= TOTAL) return;
    int p  = idx & 7;
    int oc = (idx >> 3) & 63;
    int n  = idx >> 9;
    int ox = p & 1, oy = (p >> 1) & 1, oz = p >> 2;

    const float* inb = in + (long)n * 64 * 64;
    const float* wb  = w + (long)oc * 64 * 27;

    float acc = 0.f;
    for (int ic = 0; ic < 64; ++ic) {
        const float* inc = inb + ic * 64;
        const float* wc  = wb + ic * 27;
        #pragma unroll
        for (int kz = 0; kz < 3; ++kz)
            #pragma unroll
            for (int ky = 0; ky < 3; ++ky)
                #pragma unroll
                for (int kx = 0; kx < 3; ++kx)
                    acc += wc[(kz * 3 + ky) * 3 + kx] *
                           inc[((oz + kz) * 4 + (oy + ky)) * 4 + (ox + kx)];
    }
    float v = acc + bias[oc];
    float a = slope[0];
    v = (v >= 0.f) ? v : a * v;
    out[idx] = v;
}

// ---- comm-FC ----
template<int D, int O, bool PRELU_ON>
__global__ void comm_fc_kernel(const float* __restrict__ feat,
                               const float* __restrict__ w,
                               const float* __restrict__ bias,
                               const float* __restrict__ slope,
                               float* __restrict__ out)
{
    const int a = blockIdx.x;
    const int b = blockIdx.y;

    __shared__ __align__(16) float cat[2 * D];
    for (int i = threadIdx.x; i < D; i += blockDim.x) {
        float m = 0.f;
        #pragma unroll
        for (int aa = 0; aa < 5; ++aa) m += feat[(b * 5 + aa) * D + i];
        cat[i]     = feat[(b * 5 + a) * D + i];
        cat[D + i] = m * 0.2f;
    }
    __syncthreads();

    for (int o = threadIdx.x; o < O; o += blockDim.x) {
        const float4* wr = (const float4*)(w + ((long)(a * O) + o) * 2 * D);
        const float4* cr = (const float4*)cat;
        float acc = 0.f;
        for (int i = 0; i < 2 * D / 4; ++i) {
            float4 wv = wr[i];
            float4 cv = cr[i];
            acc += wv.x * cv.x + wv.y * cv.y + wv.z * cv.z + wv.w * cv.w;
        }
        acc += bias[a * O + o];
        if constexpr (PRELU_ON) {
            float s = slope[0];
            acc = (acc >= 0.f) ? acc : s * acc;
        }
        out[(b * 5 + a) * O + o] = acc;
    }
}

extern "C" void kernel_launch(void* const* d_in, const int* in_sizes, int n_in,
                              void* d_out, int out_size, void* d_ws, size_t ws_size,
                              hipStream_t stream)
{
    const float* x    = (const float*)d_in[0];
    const float* c0w  = (const float*)d_in[1];
    const float* c0b  = (const float*)d_in[2];
    const float* p0   = (const float*)d_in[3];
    const float* c1w  = (const float*)d_in[4];
    const float* c1b  = (const float*)d_in[5];
    const float* p1   = (const float*)d_in[6];
    const float* c2w  = (const float*)d_in[7];
    const float* c2b  = (const float*)d_in[8];
    const float* p2   = (const float*)d_in[9];
    const float* c3w  = (const float*)d_in[10];
    const float* c3b  = (const float*)d_in[11];
    const float* p3   = (const float*)d_in[12];
    const float* f1w  = (const float*)d_in[13];
    const float* f1b  = (const float*)d_in[14];
    const float* p4   = (const float*)d_in[15];
    const float* f2w  = (const float*)d_in[16];
    const float* f2b  = (const float*)d_in[17];
    const float* p5   = (const float*)d_in[18];
    const float* f3w  = (const float*)d_in[19];
    const float* f3b  = (const float*)d_in[20];

    char* ws = (char*)d_ws;
    ushort* hil0 = (ushort*)(ws);                         // 67,860,480 el
    ushort* hil1 = (ushort*)(ws + 135720960);             // 65,003,520 el
    float*  P2   = (float*) (ws + 265728000);             //  3,717,120 el
    float*  P3   = (float*) (ws + 280596480);             //    327,680 el
    float*  feat0= (float*) (ws + 281907200);
    float*  feat1= (float*) (ws + 282071040);
    float*  feat2= (float*) (ws + 282152960);
    ushort* Bp0  = (ushort*)(ws + 282193920);             // 19,456 el
    ushort* Bp1  = (ushort*)(ws + 282232832);             // 128,000 el
    int4*   Dt0  = (int4*)  (ws + 282488832);             // 19
    int*    Dt1  = (int*)   (ws + 282489152);             // 125

    // zero halos of hil0/hil1 + all of P2
    hipMemsetAsync(ws, 0, 280596480, stream);

    pack_w0<<<76, 256, 0, stream>>>(c0w, Bp0, Dt0);
    pack_w1<<<500, 256, 0, stream>>>(c1w, Bp1, Dt1);
    pad_input_kernel<<<(7290000 + 255) / 256, 256, 0, stream>>>(x, hil0);

    conv0_mfma<<<dim3(441, 1, 80), 256, 0, stream>>>(hil0, Bp0, Dt0,
                                                     c0b, p0, hil1);
    conv1_mfma<<<dim3(81, 1, 80), 256, 0, stream>>>(hil1, Bp1, Dt1,
                                                    c1b, p1, P2);

    conv_pool_kernel<32, 4, 11, 12, 1452, 4, 1, 4, 0>
        <<<dim3(1, 64, 80), dim3(64), 0, stream>>>(P2, c2w, c2b, p2, P3, 1.f);

    conv3_kernel<<<dim3(160), dim3(256), 0, stream>>>(P3, c3w, c3b, p3, feat0);

    comm_fc_kernel<512, 256, true>
        <<<dim3(5, 16), dim3(256), 0, stream>>>(feat0, f1w, f1b, p4, feat1);
    comm_fc_kernel<256, 128, true>
        <<<dim3(5, 16), dim3(256), 0, stream>>>(feat1, f2w, f2b, p5, feat2);
    comm_fc_kernel<128, 6, false>
        <<<dim3(5, 16), dim3(64), 0, stream>>>(feat2, f3w, f3b, nullptr, (float*)d_out);
}

// Round 8
// 1965.548 us; speedup vs baseline: 95.5459x; 1.2711x over previous
//
#include <hip/hip_runtime.h>

// ---------------------------------------------------------------------------
// CommNet round 8: MFMA implicit GEMM with explicit 3-stage software pipeline.
//  R7 counters: conv1 MfmaUtil 14.8 / VGPR 32 -> ~2 loads in flight, pure
//  load-latency bound. Fix: rotating 3-stage register pipeline (prefetch
//  distance 2 steps), plus conv1 M flattened over (py,x) (44% -> 15% waste).
// Layouts (HW-verified): A[m=lane&15][k=q*8+j], B[n=lane&15][k=q*8+j],
//  D col=lane&15, row=q*4+reg.
// ---------------------------------------------------------------------------

typedef __attribute__((ext_vector_type(8)))  short bf16x8;
typedef __attribute__((ext_vector_type(4)))  short bf16x4;
typedef __attribute__((ext_vector_type(4)))  float f32x4;

__device__ __forceinline__ ushort f2bf(float f) {
    union { float f; unsigned u; } v; v.f = f;
    unsigned u = v.u;
    u += 0x7fff + ((u >> 16) & 1);          // RNE
    return (ushort)(u >> 16);
}
__device__ __forceinline__ float bf2f(ushort h) {
    union { unsigned u; float f; } v; v.u = ((unsigned)h) << 16;
    return v.f;
}

#define MFMA16(A, B, C) __builtin_amdgcn_mfma_f32_16x16x32_bf16(A, B, C, 0, 0, 0)

// ---- prep: x [80][4][45^3] fp32 -> hi0/lo0 NDHWC padded [80][47][47][48][4]
__global__ void pad_input_kernel(const float* __restrict__ x,
                                 ushort* __restrict__ hi, ushort* __restrict__ lo)
{
    int t = blockIdx.x * 256 + threadIdx.x;
    const int TOT = 80 * 45 * 45 * 45;
    if (t >= TOT) return;
    int xi = t % 45, r = t / 45;
    int y = r % 45; r /= 45;
    int z = r % 45; int n = r / 45;
    int ib = ((n * 4) * 91125) + z * 2025 + y * 45 + xi;
    int ob = (((n * 47 + z + 1) * 47 + y + 1) * 48 + xi + 1) * 4;
    ushort h4[4], l4[4];
    #pragma unroll
    for (int ic = 0; ic < 4; ++ic) {
        float v = x[ib + ic * 91125] * (1.f / 255.f);
        ushort h = f2bf(v);
        h4[ic] = h; l4[ic] = f2bf(v - bf2f(h));
    }
    *(ushort4*)(hi + ob) = *(ushort4*)h4;
    *(ushort4*)(lo + ob) = *(ushort4*)l4;
}

// ---- pack conv0 weights [32][4][5][5][5] -> Bp0[21 s][2 ot][64 lane][8 j]
// k = ((kz*5+ky)*6+kx)*4 + ic  (kx in [0,6), kx==5 zero; K=600, steps padded to 21)
__global__ void pack_w0(const float* __restrict__ w, ushort* __restrict__ Bp,
                        int4* __restrict__ Dt)
{
    int t = blockIdx.x * 256 + threadIdx.x;
    if (t < 21 * 2 * 64 * 8) {
        int j = t & 7, l = (t >> 3) & 63, ot = (t >> 9) & 1, s = t >> 10;
        int oc = ot * 16 + (l & 15);
        int k = 32 * s + ((l >> 4) << 3) + j;
        float v = 0.f;
        if (k < 600) {
            int ic = k & 3, t6 = k >> 2;
            int kx = t6 % 6, q = t6 / 6, ky = q % 5, kz = q / 5;
            if (kx < 5) v = w[(oc * 4 + ic) * 125 + kz * 25 + ky * 5 + kx];
        }
        Bp[t] = f2bf(v);
    }
    if (t < 21) {
        int dd[4];
        #pragma unroll
        for (int q = 0; q < 4; ++q) {
            int k = 32 * t + 8 * q;
            if (k < 600) {
                int t6 = k >> 2;
                int kx = t6 % 6, qq = t6 / 6;
                dd[q] = (((qq / 5) * 47 + (qq % 5)) * 48 + kx) * 4;  // x-unit=4
            } else dd[q] = 0;
        }
        int4 d; d.x = dd[0]; d.y = dd[1]; d.z = dd[2]; d.w = dd[3];
        Dt[t] = d;
    }
}

// ---- pack conv1 weights [32][32][5][5][5] -> Bp1[126 s][2 ot][64][8]
// step s = tap (125 real, 1 zero pad), k = s*32 + ic
__global__ void pack_w1(const float* __restrict__ w, ushort* __restrict__ Bp,
                        int* __restrict__ Dt)
{
    int t = blockIdx.x * 256 + threadIdx.x;
    if (t < 126 * 2 * 64 * 8) {
        int j = t & 7, l = (t >> 3) & 63, ot = (t >> 9) & 1, s = t >> 10;
        int oc = ot * 16 + (l & 15);
        int ic = ((l >> 4) << 3) + j;
        Bp[t] = (s < 125) ? f2bf(w[(oc * 32 + ic) * 125 + s]) : (ushort)0;
    }
    if (t < 126) {
        if (t < 125) {
            int kz = t / 25, ky = (t / 5) % 5, kx = t % 5;
            Dt[t] = ((kz * 23 + ky) * 24 + kx) * 32;                 // x-unit=32
        } else Dt[t] = 0;
    }
}

// ---- conv0 MFMA: hi0/lo0 [80][47][47][48][4] -> hi1/lo1 [80][23][23][24][32]
__global__ __launch_bounds__(256)
void conv0_mfma(const ushort* __restrict__ hi0, const ushort* __restrict__ lo0,
                const ushort* __restrict__ Bp, const int4* __restrict__ Dt,
                const float* __restrict__ bias, const float* __restrict__ slope,
                ushort* __restrict__ hi1, ushort* __restrict__ lo1)
{
    const int n  = blockIdx.z;
    const int pz = blockIdx.x / 21, py = blockIdx.x % 21;
    const int tid = threadIdx.x, lane = tid & 63, w = tid >> 6;
    const int dz = w >> 1, dy = w & 1;
    const int q = lane >> 4, l15 = lane & 15;

    __shared__ float pool[4][21][32];
    const int z0 = 2 * pz + dz, y0 = 2 * py + dy;
    const float sl = slope[0];

    int ab[3];
    #pragma unroll
    for (int xt = 0; xt < 3; ++xt) {
        int x = xt * 16 + l15;
        int xr = x > 41 ? 41 : x;
        ab[xt] = (((n * 47 + z0) * 47 + y0) * 48 + xr) * 4;
    }

    f32x4 acc[3][2] = {};
    const bf16x8* Bv = (const bf16x8*)Bp;

    constexpr int PF = 3, STEPS = 21;
    bf16x4 h0v[PF][3], h1v[PF][3], l0v[PF][3], l1v[PF][3];
    bf16x8 b0v[PF], b1v[PF];

    auto LOADS = [&](int s, int j) {
        int4 dd = Dt[s];
        int delta = q == 0 ? dd.x : q == 1 ? dd.y : q == 2 ? dd.z : dd.w;
        b0v[j] = Bv[(2 * s) * 64 + lane];
        b1v[j] = Bv[(2 * s + 1) * 64 + lane];
        #pragma unroll
        for (int xt = 0; xt < 3; ++xt) {
            int idx = ab[xt] + delta;
            h0v[j][xt] = *(const bf16x4*)(hi0 + idx);
            h1v[j][xt] = *(const bf16x4*)(hi0 + idx + 4);
            l0v[j][xt] = *(const bf16x4*)(lo0 + idx);
            l1v[j][xt] = *(const bf16x4*)(lo0 + idx + 4);
        }
    };
    auto COMP = [&](int j) {
        #pragma unroll
        for (int xt = 0; xt < 3; ++xt) {
            bf16x8 ah = __builtin_shufflevector(h0v[j][xt], h1v[j][xt], 0,1,2,3,4,5,6,7);
            bf16x8 al = __builtin_shufflevector(l0v[j][xt], l1v[j][xt], 0,1,2,3,4,5,6,7);
            acc[xt][0] = MFMA16(ah, b0v[j], acc[xt][0]);
            acc[xt][0] = MFMA16(al, b0v[j], acc[xt][0]);
            acc[xt][1] = MFMA16(ah, b1v[j], acc[xt][1]);
            acc[xt][1] = MFMA16(al, b1v[j], acc[xt][1]);
        }
    };

    LOADS(0, 0); LOADS(1, 1);
    for (int s = 0; s < STEPS; s += PF) {
        LOADS(s + 2, 2);
        COMP(0);
        if (s + 3 < STEPS) LOADS(s + 3, 0);
        COMP(1);
        if (s + 4 < STEPS) LOADS(s + 4, 1);
        COMP(2);
    }

    #pragma unroll
    for (int xt = 0; xt < 3; ++xt) {
        int pxe = xt * 8 + 2 * q, pxo = pxe + 1;
        float pe0 = fmaxf(acc[xt][0][0], acc[xt][0][1]);
        float po0 = fmaxf(acc[xt][0][2], acc[xt][0][3]);
        float pe1 = fmaxf(acc[xt][1][0], acc[xt][1][1]);
        float po1 = fmaxf(acc[xt][1][2], acc[xt][1][3]);
        if (pxe < 21) { pool[w][pxe][l15] = pe0; pool[w][pxe][16 + l15] = pe1; }
        if (pxo < 21) { pool[w][pxo][l15] = po0; pool[w][pxo][16 + l15] = po1; }
    }
    __syncthreads();

    for (int t2 = tid; t2 < 672; t2 += 256) {
        int oc = t2 & 31, px = t2 >> 5;
        float v = fmaxf(fmaxf(pool[0][px][oc], pool[1][px][oc]),
                        fmaxf(pool[2][px][oc], pool[3][px][oc]));
        v += bias[oc];
        v = (v >= 0.f) ? v : sl * v;
        int o = (((n * 23 + pz + 1) * 23 + py + 1) * 24 + px + 1) * 32 + oc;
        ushort h = f2bf(v);
        hi1[o] = h; lo1[o] = f2bf(v - bf2f(h));
    }
}

// ---- conv1 MFMA: hi1/lo1 [80][23][23][24][32] -> P2 fp32 NCDHW padded
// block = (n, pz, py-group of 3); wave = (dz,dy); M flattened over (py_local,x):
// flat = pyl*18 + x in [0,54), 4 m-tiles of 16 (15.6% waste).
__global__ __launch_bounds__(256)
void conv1_mfma(const ushort* __restrict__ hi1, const ushort* __restrict__ lo1,
                const ushort* __restrict__ Bp, const int* __restrict__ Dt,
                const float* __restrict__ bias, const float* __restrict__ slope,
                float* __restrict__ P2)
{
    const int n   = blockIdx.z;
    const int pz  = blockIdx.x / 3, pyg = blockIdx.x % 3;
    const int tid = threadIdx.x, lane = tid & 63, w = tid >> 6;
    const int dz = w >> 1, dy = w & 1;
    const int q = lane >> 4, l15 = lane & 15;

    __shared__ float pool[4][27][32];
    const int z0 = 2 * pz + dz;

    int ab[4];
    #pragma unroll
    for (int t = 0; t < 4; ++t) {
        int flat = t * 16 + l15;
        if (flat > 53) flat = 53;
        int pyl = flat / 18, x = flat - pyl * 18;
        int y0 = 2 * (pyg * 3 + pyl) + dy;
        ab[t] = ((((n * 23 + z0) * 23 + y0) * 24 + x) << 5) + q * 8;
    }

    f32x4 acc[4][2] = {};
    const bf16x8* Bv = (const bf16x8*)Bp;

    constexpr int PF = 3, STEPS = 126;
    bf16x8 ahv[PF][4], alv[PF][4], b0v[PF], b1v[PF];

    auto LOADS = [&](int s, int j) {
        int off = Dt[s];
        b0v[j] = Bv[(2 * s) * 64 + lane];
        b1v[j] = Bv[(2 * s + 1) * 64 + lane];
        #pragma unroll
        for (int t = 0; t < 4; ++t) {
            ahv[j][t] = *(const bf16x8*)(hi1 + ab[t] + off);
            alv[j][t] = *(const bf16x8*)(lo1 + ab[t] + off);
        }
    };
    auto COMP = [&](int j) {
        #pragma unroll
        for (int t = 0; t < 4; ++t) {
            acc[t][0] = MFMA16(ahv[j][t], b0v[j], acc[t][0]);
            acc[t][0] = MFMA16(alv[j][t], b0v[j], acc[t][0]);
            acc[t][1] = MFMA16(ahv[j][t], b1v[j], acc[t][1]);
            acc[t][1] = MFMA16(alv[j][t], b1v[j], acc[t][1]);
        }
    };

    LOADS(0, 0); LOADS(1, 1);
    for (int s = 0; s < STEPS; s += PF) {
        LOADS(s + 2, 2);
        COMP(0);
        if (s + 3 < STEPS) LOADS(s + 3, 0);
        COMP(1);
        if (s + 4 < STEPS) LOADS(s + 4, 1);
        COMP(2);
    }

    // D rows m=q*4+reg of tile t -> flat = t*16+q*4+reg; x-pairs = (reg0,reg1),(reg2,reg3)
    #pragma unroll
    for (int t = 0; t < 4; ++t) {
        int p0 = t * 8 + q * 2;
        float e0 = fmaxf(acc[t][0][0], acc[t][0][1]);
        float o0 = fmaxf(acc[t][0][2], acc[t][0][3]);
        float e1 = fmaxf(acc[t][1][0], acc[t][1][1]);
        float o1 = fmaxf(acc[t][1][2], acc[t][1][3]);
        if (p0 < 27)     { pool[w][p0][l15] = e0;     pool[w][p0][16 + l15] = e1; }
        if (p0 + 1 < 27) { pool[w][p0 + 1][l15] = o0; pool[w][p0 + 1][16 + l15] = o1; }
    }
    __syncthreads();

    for (int t2 = tid; t2 < 864; t2 += 256) {
        int oc = t2 & 31, pr = t2 >> 5;          // pr = pyl*9 + px
        int pyl = pr / 9, px = pr % 9;
        float v = fmaxf(fmaxf(pool[0][pr][oc], pool[1][pr][oc]),
                        fmaxf(pool[2][pr][oc], pool[3][pr][oc]));
        v += bias[oc];
        float s0 = slope[0];
        v = (v >= 0.f) ? v : s0 * v;
        int py = pyg * 3 + pyl;
        P2[(long)n * 32 * 11 * 11 * 12 +
           ((oc * 11 + pz + 1) * 11 + py + 1) * 12 + px + 1] = v;
    }
}

// ---- conv2 (fp32 direct, R4-verified) ----
template<int CIN, int K, int SY, int SXS, int ICS, int SPOOL, int PX,
         int OXS, int OPAD>
__global__ __launch_bounds__(256, 2)
void conv_pool_kernel(const float* __restrict__ in,
                      const float* __restrict__ w,
                      const float* __restrict__ bias,
                      const float* __restrict__ slope,
                      float* __restrict__ out,
                      float scale)
{
    constexpr int NX  = 2 * PX;
    constexpr int LX  = NX + K - 1;
    constexpr int LX2 = (LX + 1) / 2;
    constexpr int XT  = SPOOL / PX;
    constexpr int OD  = SPOOL + 2 * OPAD;

    const int oc   = blockIdx.y;
    const int n    = blockIdx.z;
    const int COUT = gridDim.y;

    int idx = blockIdx.x * blockDim.x + threadIdx.x;
    const int POS = XT * SPOOL * SPOOL;
    if (idx >= POS) return;

    int xt  = idx % XT;
    int py  = (idx / XT) % SPOOL;
    int pz  = idx / (XT * SPOOL);
    int px0 = xt * PX;

    const float* inb = in + (long)n * CIN * ICS + (2 * pz * SY + 2 * py) * SXS + 2 * px0;
    const float* wb  = w + (long)oc * CIN * K * K * K;

    float acc[2][2][NX] = {};

    #pragma unroll 1
    for (int ic = 0; ic < CIN; ++ic) {
        const float* inc = inb + (long)ic * ICS;
        const float* wic = wb + ic * K * K * K;
        #pragma unroll
        for (int tz = 0; tz < K + 1; ++tz) {
            #pragma unroll
            for (int ty = 0; ty < K + 1; ++ty) {
                const float2* rp = (const float2*)(inc + (tz * SY + ty) * SXS);
                float row[LX2 * 2];
                #pragma unroll
                for (int i = 0; i < LX2; ++i) {
                    float2 t = rp[i];
                    row[2 * i] = t.x; row[2 * i + 1] = t.y;
                }
                #pragma unroll
                for (int dzz = 0; dzz < 2; ++dzz) {
                    if (tz - dzz < 0 || tz - dzz >= K) continue;
                    #pragma unroll
                    for (int dyy = 0; dyy < 2; ++dyy) {
                        if (ty - dyy < 0 || ty - dyy >= K) continue;
                        const float* wrow = wic + ((tz - dzz) * K + (ty - dyy)) * K;
                        #pragma unroll
                        for (int kx = 0; kx < K; ++kx) {
                            float wv = wrow[kx];
                            #pragma unroll
                            for (int dx = 0; dx < NX; ++dx)
                                acc[dzz][dyy][dx] += wv * row[kx + dx];
                        }
                    }
                }
            }
        }
    }

    float b = bias[oc];
    float a = slope[0];
    long ob = ((long)n * COUT + oc) * (OD * OD * OXS)
            + (long)(pz + OPAD) * (OD * OXS) + (py + OPAD) * OXS + OPAD + px0;
    #pragma unroll
    for (int j = 0; j < PX; ++j) {
        float m = -3.4e38f;
        #pragma unroll
        for (int dzz = 0; dzz < 2; ++dzz)
            #pragma unroll
            for (int dyy = 0; dyy < 2; ++dyy)
                #pragma unroll
                for (int dx = 0; dx < 2; ++dx) {
                    float v = acc[dzz][dyy][2 * j + dx] * scale + b;
                    v = (v >= 0.f) ? v : a * v;
                    m = fmaxf(m, v);
                }
        out[ob + j] = m;
    }
}

// ---- conv3 (fp32 direct) ----
__global__ void conv3_kernel(const float* __restrict__ in,
                             const float* __restrict__ w,
                             const float* __restrict__ bias,
                             const float* __restrict__ slope,
                             float* __restrict__ out)
{
    int idx = blockIdx.x * blockDim.x + threadIdx.x;
    const int TOTAL = 80 * 64 * 8;
    if (idx >= TOTAL) return;
    int p  = idx & 7;
    int oc = (idx >> 3) & 63;
    int n  = idx >> 9;
    int ox = p & 1, oy = (p >> 1) & 1, oz = p >> 2;

    const float* inb = in + (long)n * 64 * 64;
    const float* wb  = w + (long)oc * 64 * 27;

    float acc = 0.f;
    for (int ic = 0; ic < 64; ++ic) {
        const float* inc = inb + ic * 64;
        const float* wc  = wb + ic * 27;
        #pragma unroll
        for (int kz = 0; kz < 3; ++kz)
            #pragma unroll
            for (int ky = 0; ky < 3; ++ky)
                #pragma unroll
                for (int kx = 0; kx < 3; ++kx)
                    acc += wc[(kz * 3 + ky) * 3 + kx] *
                           inc[((oz + kz) * 4 + (oy + ky)) * 4 + (ox + kx)];
    }
    float v = acc + bias[oc];
    float a = slope[0];
    v = (v >= 0.f) ? v : a * v;
    out[idx] = v;
}

// ---- comm-FC ----
template<int D, int O, bool PRELU_ON>
__global__ void comm_fc_kernel(const float* __restrict__ feat,
                               const float* __restrict__ w,
                               const float* __restrict__ bias,
                               const float* __restrict__ slope,
                               float* __restrict__ out)
{
    const int a = blockIdx.x;
    const int b = blockIdx.y;

    __shared__ __align__(16) float cat[2 * D];
    for (int i = threadIdx.x; i < D; i += blockDim.x) {
        float m = 0.f;
        #pragma unroll
        for (int aa = 0; aa < 5; ++aa) m += feat[(b * 5 + aa) * D + i];
        cat[i]     = feat[(b * 5 + a) * D + i];
        cat[D + i] = m * 0.2f;
    }
    __syncthreads();

    for (int o = threadIdx.x; o < O; o += blockDim.x) {
        const float4* wr = (const float4*)(w + ((long)(a * O) + o) * 2 * D);
        const float4* cr = (const float4*)cat;
        float acc = 0.f;
        for (int i = 0; i < 2 * D / 4; ++i) {
            float4 wv = wr[i];
            float4 cv = cr[i];
            acc += wv.x * cv.x + wv.y * cv.y + wv.z * cv.z + wv.w * cv.w;
        }
        acc += bias[a * O + o];
        if constexpr (PRELU_ON) {
            float s = slope[0];
            acc = (acc >= 0.f) ? acc : s * acc;
        }
        out[(b * 5 + a) * O + o] = acc;
    }
}

extern "C" void kernel_launch(void* const* d_in, const int* in_sizes, int n_in,
                              void* d_out, int out_size, void* d_ws, size_t ws_size,
                              hipStream_t stream)
{
    const float* x    = (const float*)d_in[0];
    const float* c0w  = (const float*)d_in[1];
    const float* c0b  = (const float*)d_in[2];
    const float* p0   = (const float*)d_in[3];
    const float* c1w  = (const float*)d_in[4];
    const float* c1b  = (const float*)d_in[5];
    const float* p1   = (const float*)d_in[6];
    const float* c2w  = (const float*)d_in[7];
    const float* c2b  = (const float*)d_in[8];
    const float* p2   = (const float*)d_in[9];
    const float* c3w  = (const float*)d_in[10];
    const float* c3b  = (const float*)d_in[11];
    const float* p3   = (const float*)d_in[12];
    const float* f1w  = (const float*)d_in[13];
    const float* f1b  = (const float*)d_in[14];
    const float* p4   = (const float*)d_in[15];
    const float* f2w  = (const float*)d_in[16];
    const float* f2b  = (const float*)d_in[17];
    const float* p5   = (const float*)d_in[18];
    const float* f3w  = (const float*)d_in[19];
    const float* f3b  = (const float*)d_in[20];

    char* ws = (char*)d_ws;
    ushort* hi0  = (ushort*)(ws);                         // 33,930,240 el
    ushort* lo0  = (ushort*)(ws + 67860480);
    ushort* hi1  = (ushort*)(ws + 135720960);             // 32,501,760 el
    ushort* lo1  = (ushort*)(ws + 200724480);
    float*  P2   = (float*) (ws + 265728000);             //  3,717,120 el
    float*  P3   = (float*) (ws + 280596480);             //    327,680 el
    float*  feat0= (float*) (ws + 281907200);
    float*  feat1= (float*) (ws + 282071040);
    float*  feat2= (float*) (ws + 282152960);
    ushort* Bp0  = (ushort*)(ws + 282193920);             // 21,504 el
    ushort* Bp1  = (ushort*)(ws + 282236928);             // 129,024 el
    int4*   Dt0  = (int4*)  (ws + 282494976);             // 21
    int*    Dt1  = (int*)   (ws + 282495312);             // 126

    // zero halos of hi0/lo0/hi1/lo1 + all of P2
    hipMemsetAsync(ws, 0, 280596480, stream);

    pack_w0<<<84, 256, 0, stream>>>(c0w, Bp0, Dt0);
    pack_w1<<<504, 256, 0, stream>>>(c1w, Bp1, Dt1);
    pad_input_kernel<<<(7290000 + 255) / 256, 256, 0, stream>>>(x, hi0, lo0);

    conv0_mfma<<<dim3(441, 1, 80), 256, 0, stream>>>(hi0, lo0, Bp0, Dt0,
                                                     c0b, p0, hi1, lo1);
    conv1_mfma<<<dim3(27, 1, 80), 256, 0, stream>>>(hi1, lo1, Bp1, Dt1,
                                                    c1b, p1, P2);

    conv_pool_kernel<32, 4, 11, 12, 1452, 4, 1, 4, 0>
        <<<dim3(1, 64, 80), dim3(64), 0, stream>>>(P2, c2w, c2b, p2, P3, 1.f);

    conv3_kernel<<<dim3(160), dim3(256), 0, stream>>>(P3, c3w, c3b, p3, feat0);

    comm_fc_kernel<512, 256, true>
        <<<dim3(5, 16), dim3(256), 0, stream>>>(feat0, f1w, f1b, p4, feat1);
    comm_fc_kernel<256, 128, true>
        <<<dim3(5, 16), dim3(256), 0, stream>>>(feat1, f2w, f2b, p5, feat2);
    comm_fc_kernel<128, 6, false>
        <<<dim3(5, 16), dim3(64), 0, stream>>>(feat2, f3w, f3b, nullptr, (float*)d_out);
}